// Round 1
// baseline (565.996 us; speedup 1.0000x reference)
//
#include <hip/hip_runtime.h>

#define N_NODES 50000
#define N_EDGES 800000
#define IN_DIM 128
#define EMB_DIM 64
#define HID 128
#define OUT_DIM 64
#define NUM_GRAPHS 128
#define E_TOT (N_EDGES + N_NODES)

__device__ __forceinline__ float gelu_f(float x) {
    // jax.nn.gelu default approximate=True (tanh form)
    float x3 = x * x * x;
    return 0.5f * x * (1.0f + tanhf(0.7978845608028654f * (x + 0.044715f * x3)));
}
__device__ __forceinline__ float lrelu02(float x) { return x > 0.f ? x : 0.2f * x; }

// ---------- normalize x rows -> xn [N,128] ----------
__global__ __launch_bounds__(256) void k_norm(const float* __restrict__ x,
                                              float* __restrict__ xn) {
    int lane = threadIdx.x & 63;
    int node = (blockIdx.x * 256 + threadIdx.x) >> 6;
    if (node >= N_NODES) return;
    const float2* xr = (const float2*)(x + (size_t)node * IN_DIM);
    float2 v = xr[lane];
    float ss = v.x * v.x + v.y * v.y;
#pragma unroll
    for (int o = 32; o; o >>= 1) ss += __shfl_xor(ss, o);
    float nrm = sqrtf(ss);
    if (nrm == 0.f) nrm = 1e-8f;
    float inv = 1.f / nrm;
    ((float2*)(xn + (size_t)node * IN_DIM))[lane] = make_float2(v.x * inv, v.y * inv);
}

// ---------- degree histogram over dst ----------
__global__ __launch_bounds__(256) void k_deg(const int* __restrict__ dst, int* __restrict__ deg) {
    int e = blockIdx.x * 256 + threadIdx.x;
    if (e < N_EDGES) atomicAdd(&deg[dst[e]], 1);
}

// ---------- scan step A: per-block sums of (deg+1)  (+1 = self loop) ----------
__global__ __launch_bounds__(256) void k_scanA(const int* __restrict__ deg, int* __restrict__ bsum) {
    __shared__ int sh[256];
    int i = blockIdx.x * 256 + threadIdx.x;
    int v = (i < N_NODES) ? deg[i] + 1 : 0;
    sh[threadIdx.x] = v;
    __syncthreads();
    for (int o = 128; o; o >>= 1) {
        if (threadIdx.x < o) sh[threadIdx.x] += sh[threadIdx.x + o];
        __syncthreads();
    }
    if (threadIdx.x == 0) bsum[blockIdx.x] = sh[0];
}

// ---------- scan step B: exclusive scan of block sums (nb <= 256) ----------
__global__ __launch_bounds__(256) void k_scanB(const int* __restrict__ bsum, int* __restrict__ boff, int nb) {
    __shared__ int sh[256];
    int t = threadIdx.x;
    int v = (t < nb) ? bsum[t] : 0;
    sh[t] = v;
    __syncthreads();
    for (int o = 1; o < 256; o <<= 1) {
        int u = (t >= o) ? sh[t - o] : 0;
        __syncthreads();
        sh[t] += u;
        __syncthreads();
    }
    boff[t] = sh[t] - v;  // exclusive
}

// ---------- scan step C: rowptr ----------
__global__ __launch_bounds__(256) void k_scanC(const int* __restrict__ deg, const int* __restrict__ boff,
                                               int* __restrict__ rowptr) {
    __shared__ int sh[256];
    int t = threadIdx.x;
    int i = blockIdx.x * 256 + t;
    int v = (i < N_NODES) ? deg[i] + 1 : 0;
    sh[t] = v;
    __syncthreads();
    for (int o = 1; o < 256; o <<= 1) {
        int u = (t >= o) ? sh[t - o] : 0;
        __syncthreads();
        sh[t] += u;
        __syncthreads();
    }
    int excl = sh[t] - v + boff[blockIdx.x];
    if (i < N_NODES) rowptr[i] = excl;
    if (i == N_NODES - 1) rowptr[N_NODES] = excl + v;
}

// ---------- fill CSR (edges + self loops) ----------
__global__ __launch_bounds__(256) void k_fill(const int* __restrict__ src, const int* __restrict__ dst,
                                              const int* __restrict__ rowptr, int* __restrict__ fillc,
                                              int* __restrict__ csr) {
    int t = blockIdx.x * 256 + threadIdx.x;
    if (t >= E_TOT) return;
    int s, d;
    if (t < N_EDGES) { s = src[t]; d = dst[t]; }
    else { s = d = t - N_EDGES; }
    int p = rowptr[d] + atomicAdd(&fillc[d], 1);
    csr[p] = s;
}

// ---------- GEMM: H = A@W (+ emb[nidx]@W[KA:]), asn = H.a_s, adn = H.a_d ----------
// one wave handles 8 rows; lane -> cols (lane, lane+64); A loads are wave-uniform (s_load)
template <int KA, int KE>
__global__ __launch_bounds__(256) void k_gemm(const float* __restrict__ A,
                                              const float* __restrict__ embT, const int* __restrict__ nidx,
                                              const float* __restrict__ W,
                                              const float* __restrict__ a_s, const float* __restrict__ a_d,
                                              float* __restrict__ H, float* __restrict__ asn,
                                              float* __restrict__ adn) {
    int lane = threadIdx.x & 63;
    int wid = (blockIdx.x * 256 + threadIdx.x) >> 6;
    int rowbase = __builtin_amdgcn_readfirstlane(wid * 8);
    if (rowbase >= N_NODES) return;
    int c0 = lane, c1 = lane + 64;
    float acc[8][2];
#pragma unroll
    for (int r = 0; r < 8; r++) { acc[r][0] = 0.f; acc[r][1] = 0.f; }
    const float* Ab = A + (size_t)rowbase * KA;
#pragma unroll 4
    for (int k = 0; k < KA; k++) {
        float w0 = W[k * HID + c0];
        float w1 = W[k * HID + c1];
#pragma unroll
        for (int r = 0; r < 8; r++) {
            float a = Ab[r * KA + k];
            acc[r][0] = fmaf(a, w0, acc[r][0]);
            acc[r][1] = fmaf(a, w1, acc[r][1]);
        }
    }
    if constexpr (KE > 0) {
        int nid[8];
#pragma unroll
        for (int r = 0; r < 8; r++) nid[r] = __builtin_amdgcn_readfirstlane(nidx[rowbase + r]);
#pragma unroll 4
        for (int k2 = 0; k2 < KE; k2++) {
            int k = KA + k2;
            float w0 = W[k * HID + c0];
            float w1 = W[k * HID + c1];
#pragma unroll
            for (int r = 0; r < 8; r++) {
                float a = embT[nid[r] * KE + k2];
                acc[r][0] = fmaf(a, w0, acc[r][0]);
                acc[r][1] = fmaf(a, w1, acc[r][1]);
            }
        }
    }
    float as0 = a_s[c0], as1 = a_s[c1];
    float ad0 = a_d[c0], ad1 = a_d[c1];
#pragma unroll
    for (int r = 0; r < 8; r++) {
        int row = rowbase + r;
        float h0 = acc[r][0], h1 = acc[r][1];
        H[(size_t)row * HID + c0] = h0;
        H[(size_t)row * HID + c1] = h1;
        float ps = h0 * as0 + h1 * as1;
        float pd = h0 * ad0 + h1 * ad1;
#pragma unroll
        for (int o = 32; o; o >>= 1) {
            ps += __shfl_xor(ps, o);
            pd += __shfl_xor(pd, o);
        }
        if (lane == 0) { asn[row] = ps; adn[row] = pd; }
    }
}

// ---------- GAT aggregation: wave per dst node, segment softmax + weighted sum + gelu ----------
__global__ __launch_bounds__(256) void k_aggr(const int* __restrict__ rowptr, const int* __restrict__ csr,
                                              const float* __restrict__ asn, const float* __restrict__ adn,
                                              const float* __restrict__ h, const float* __restrict__ bias,
                                              float* __restrict__ out) {
    __shared__ float sh_e[4][64];
    __shared__ int sh_s[4][64];
    int lane = threadIdx.x & 63;
    int w = threadIdx.x >> 6;
    int node = blockIdx.x * 4 + w;
    if (node >= N_NODES) return;
    int st = rowptr[node], en = rowptr[node + 1];
    float ad = adn[node];
    // pass 1: segment max
    float m = -1e30f;
    for (int i = st + lane; i < en; i += 64) {
        float l = lrelu02(asn[csr[i]] + ad);
        m = fmaxf(m, l);
    }
#pragma unroll
    for (int o = 32; o; o >>= 1) m = fmaxf(m, __shfl_xor(m, o));
    // pass 2: exp-sum
    float ssum = 0.f;
    for (int i = st + lane; i < en; i += 64) {
        float l = lrelu02(asn[csr[i]] + ad);
        ssum += __expf(l - m);
    }
#pragma unroll
    for (int o = 32; o; o >>= 1) ssum += __shfl_xor(ssum, o);
    float inv = 1.f / ssum;
    // pass 3: weighted channel accumulation (chunks of 64 edges)
    float2 acc = make_float2(0.f, 0.f);
    const float2* h2 = (const float2*)h;
    for (int base = st; base < en; base += 64) {
        int cnt = min(64, en - base);
        if (lane < cnt) {
            int s = csr[base + lane];
            float l = lrelu02(asn[s] + ad);
            sh_e[w][lane] = __expf(l - m) * inv;
            sh_s[w][lane] = s;
        }
        // same-wave LDS write->read: in-order DS pipe + compiler lgkmcnt
        for (int j = 0; j < cnt; j++) {
            float coef = sh_e[w][j];
            int s = sh_s[w][j];
            float2 hv = h2[(size_t)s * 64 + lane];
            acc.x = fmaf(coef, hv.x, acc.x);
            acc.y = fmaf(coef, hv.y, acc.y);
        }
    }
    float2 b = ((const float2*)bias)[lane];
    float2 res;
    res.x = gelu_f(acc.x + b.x);
    res.y = gelu_f(acc.y + b.y);
    ((float2*)out)[(size_t)node * 64 + lane] = res;
}

// ---------- global_add_pool: batch is sorted, register-accumulate per channel ----------
__global__ __launch_bounds__(128) void k_pool(const float* __restrict__ h, const int* __restrict__ batch,
                                              float* __restrict__ g) {
    int c = threadIdx.x;  // 0..127
    int n0 = blockIdx.x * 128;
    if (n0 >= N_NODES) return;
    int n1 = min(n0 + 128, N_NODES);
    int cur = batch[n0];
    float acc = 0.f;
    for (int n = n0; n < n1; n++) {
        int b = batch[n];
        if (b != cur) {
            atomicAdd(&g[cur * HID + c], acc);
            acc = 0.f;
            cur = b;
        }
        acc += h[(size_t)n * HID + c];
    }
    atomicAdd(&g[cur * HID + c], acc);
}

// ---------- final fc + leaky_relu(0.01) ----------
__global__ __launch_bounds__(256) void k_fc(const float* __restrict__ g, const float* __restrict__ fcW,
                                            const float* __restrict__ fcb, float* __restrict__ out) {
    int tid = blockIdx.x * 256 + threadIdx.x;
    if (tid >= NUM_GRAPHS * OUT_DIM) return;
    int gr = tid >> 6;  // OUT_DIM = 64
    int c = tid & 63;
    float acc = fcb[c];
    const float* grow = g + gr * HID;
#pragma unroll 4
    for (int k = 0; k < HID; k++) acc = fmaf(grow[k], fcW[k * OUT_DIM + c], acc);
    out[tid] = acc > 0.f ? acc : 0.01f * acc;
}

extern "C" void kernel_launch(void* const* d_in, const int* in_sizes, int n_in,
                              void* d_out, int out_size, void* d_ws, size_t ws_size,
                              hipStream_t stream) {
    const float* x    = (const float*)d_in[0];
    const int* nidx   = (const int*)d_in[1];
    const int* ei     = (const int*)d_in[2];
    const int* batch  = (const int*)d_in[3];
    const float* emb  = (const float*)d_in[4];
    const float* W1   = (const float*)d_in[5];
    const float* a1s  = (const float*)d_in[6];
    const float* a1d  = (const float*)d_in[7];
    const float* b1   = (const float*)d_in[8];
    const float* W2   = (const float*)d_in[9];
    const float* a2s  = (const float*)d_in[10];
    const float* a2d  = (const float*)d_in[11];
    const float* b2   = (const float*)d_in[12];
    const float* W3   = (const float*)d_in[13];
    const float* a3s  = (const float*)d_in[14];
    const float* a3d  = (const float*)d_in[15];
    const float* b3   = (const float*)d_in[16];
    const float* fcW  = (const float*)d_in[17];
    const float* fcb  = (const float*)d_in[18];
    float* out = (float*)d_out;
    const int* srcA = ei;
    const int* dstA = ei + N_EDGES;

    char* w = (char*)d_ws;
    auto alloc = [&](size_t bytes) -> char* {
        char* p = w;
        w += (bytes + 511) & ~(size_t)511;
        return p;
    };
    float* hA    = (float*)alloc((size_t)N_NODES * HID * 4);   // 25.6 MB
    float* hB    = (float*)alloc((size_t)N_NODES * HID * 4);   // 25.6 MB
    float* asn   = (float*)alloc((size_t)N_NODES * 4);
    float* adn   = (float*)alloc((size_t)N_NODES * 4);
    int* rowptr  = (int*)alloc((size_t)(N_NODES + 1) * 4);
    int* deg     = (int*)alloc((size_t)N_NODES * 4);
    int* fillc   = (int*)alloc((size_t)N_NODES * 4);
    int* bsum    = (int*)alloc(1024);
    int* boff    = (int*)alloc(1024);
    int* csr     = (int*)alloc((size_t)E_TOT * 4);             // 3.4 MB
    float* g     = (float*)alloc((size_t)NUM_GRAPHS * HID * 4);

    hipMemsetAsync(deg, 0, (size_t)N_NODES * 4, stream);
    hipMemsetAsync(fillc, 0, (size_t)N_NODES * 4, stream);
    hipMemsetAsync(g, 0, (size_t)NUM_GRAPHS * HID * 4, stream);

    int nb = (N_NODES + 255) / 256;  // 196 scan blocks
    k_norm<<<(N_NODES + 3) / 4, 256, 0, stream>>>(x, hB);
    k_deg<<<(N_EDGES + 255) / 256, 256, 0, stream>>>(dstA, deg);
    k_scanA<<<nb, 256, 0, stream>>>(deg, bsum);
    k_scanB<<<1, 256, 0, stream>>>(bsum, boff, nb);
    k_scanC<<<nb, 256, 0, stream>>>(deg, boff, rowptr);
    k_fill<<<(E_TOT + 255) / 256, 256, 0, stream>>>(srcA, dstA, rowptr, fillc, csr);

    int gemmBlocks = (((N_NODES + 7) / 8) + 3) / 4;  // 1563
    int aggrBlocks = (N_NODES + 3) / 4;              // 12500

    k_gemm<IN_DIM, EMB_DIM><<<gemmBlocks, 256, 0, stream>>>(hB, emb, nidx, W1, a1s, a1d, hA, asn, adn);
    k_aggr<<<aggrBlocks, 256, 0, stream>>>(rowptr, csr, asn, adn, hA, b1, hB);
    k_gemm<HID, 0><<<gemmBlocks, 256, 0, stream>>>(hB, nullptr, nullptr, W2, a2s, a2d, hA, asn, adn);
    k_aggr<<<aggrBlocks, 256, 0, stream>>>(rowptr, csr, asn, adn, hA, b2, hB);
    k_gemm<HID, 0><<<gemmBlocks, 256, 0, stream>>>(hB, nullptr, nullptr, W3, a3s, a3d, hA, asn, adn);
    k_aggr<<<aggrBlocks, 256, 0, stream>>>(rowptr, csr, asn, adn, hA, b3, hB);

    k_pool<<<(N_NODES + 127) / 128, 128, 0, stream>>>(hB, batch, g);
    k_fc<<<(NUM_GRAPHS * OUT_DIM + 255) / 256, 256, 0, stream>>>(g, fcW, fcb, out);
}

// Round 2
// 545.811 us; speedup vs baseline: 1.0370x; 1.0370x over previous
//
#include <hip/hip_runtime.h>

#define N_NODES 50000
#define N_EDGES 800000
#define IN_DIM 128
#define EMB_DIM 64
#define HID 128
#define OUT_DIM 64
#define NUM_GRAPHS 128
#define E_TOT (N_EDGES + N_NODES)

__device__ __forceinline__ float gelu_f(float x) {
    // jax.nn.gelu default approximate=True (tanh form)
    float x3 = x * x * x;
    return 0.5f * x * (1.0f + tanhf(0.7978845608028654f * (x + 0.044715f * x3)));
}
__device__ __forceinline__ float lrelu02(float x) { return x > 0.f ? x : 0.2f * x; }
__device__ __forceinline__ float rl_f(float v, int j) {
    return __int_as_float(__builtin_amdgcn_readlane(__float_as_int(v), j));
}

// ---------- row inverse-norms of x  (no xn materialization) ----------
__global__ __launch_bounds__(256) void k_norms(const float* __restrict__ x,
                                               float* __restrict__ ninv) {
    int lane = threadIdx.x & 63;
    int node = (blockIdx.x * 256 + threadIdx.x) >> 6;
    if (node >= N_NODES) return;
    const float2* xr = (const float2*)(x + (size_t)node * IN_DIM);
    float2 v = xr[lane];
    float ss = v.x * v.x + v.y * v.y;
#pragma unroll
    for (int o = 32; o; o >>= 1) ss += __shfl_xor(ss, o);
    if (lane == 0) {
        float nrm = sqrtf(ss);
        if (nrm == 0.f) nrm = 1e-8f;
        ninv[node] = 1.f / nrm;
    }
}

// ---------- degree histogram over dst ----------
__global__ __launch_bounds__(256) void k_deg(const int* __restrict__ dst, int* __restrict__ deg) {
    int e = blockIdx.x * 256 + threadIdx.x;
    if (e < N_EDGES) atomicAdd(&deg[dst[e]], 1);
}

// ---------- scan step A: per-block sums of (deg+1)  (+1 = self loop) ----------
__global__ __launch_bounds__(256) void k_scanA(const int* __restrict__ deg, int* __restrict__ bsum) {
    __shared__ int sh[256];
    int i = blockIdx.x * 256 + threadIdx.x;
    int v = (i < N_NODES) ? deg[i] + 1 : 0;
    sh[threadIdx.x] = v;
    __syncthreads();
    for (int o = 128; o; o >>= 1) {
        if (threadIdx.x < o) sh[threadIdx.x] += sh[threadIdx.x + o];
        __syncthreads();
    }
    if (threadIdx.x == 0) bsum[blockIdx.x] = sh[0];
}

// ---------- scan step B: exclusive scan of block sums (nb <= 256) ----------
__global__ __launch_bounds__(256) void k_scanB(const int* __restrict__ bsum, int* __restrict__ boff, int nb) {
    __shared__ int sh[256];
    int t = threadIdx.x;
    int v = (t < nb) ? bsum[t] : 0;
    sh[t] = v;
    __syncthreads();
    for (int o = 1; o < 256; o <<= 1) {
        int u = (t >= o) ? sh[t - o] : 0;
        __syncthreads();
        sh[t] += u;
        __syncthreads();
    }
    boff[t] = sh[t] - v;  // exclusive
}

// ---------- scan step C: rowptr ----------
__global__ __launch_bounds__(256) void k_scanC(const int* __restrict__ deg, const int* __restrict__ boff,
                                               int* __restrict__ rowptr) {
    __shared__ int sh[256];
    int t = threadIdx.x;
    int i = blockIdx.x * 256 + t;
    int v = (i < N_NODES) ? deg[i] + 1 : 0;
    sh[t] = v;
    __syncthreads();
    for (int o = 1; o < 256; o <<= 1) {
        int u = (t >= o) ? sh[t - o] : 0;
        __syncthreads();
        sh[t] += u;
        __syncthreads();
    }
    int excl = sh[t] - v + boff[blockIdx.x];
    if (i < N_NODES) rowptr[i] = excl;
    if (i == N_NODES - 1) rowptr[N_NODES] = excl + v;
}

// ---------- fill CSR (edges + self loops) ----------
__global__ __launch_bounds__(256) void k_fill(const int* __restrict__ src, const int* __restrict__ dst,
                                              const int* __restrict__ rowptr, int* __restrict__ fillc,
                                              int* __restrict__ csr) {
    int t = blockIdx.x * 256 + threadIdx.x;
    if (t >= E_TOT) return;
    int s, d;
    if (t < N_EDGES) { s = src[t]; d = dst[t]; }
    else { s = d = t - N_EDGES; }
    int p = rowptr[d] + atomicAdd(&fillc[d], 1);
    csr[p] = s;
}

// ---------- GEMM: H = A@W (+ emb[nidx]@W[KA:]), asn = H.a_s, adn = H.a_d ----------
// one wave handles 8 rows; lane -> cols (lane, lane+64); A loads are wave-uniform (s_load).
// NRM: scale the KA-part accumulator by ninv[row] (folds x/||x|| into the GEMM).
template <int KA, int KE, bool NRM>
__global__ __launch_bounds__(256) void k_gemm(const float* __restrict__ A,
                                              const float* __restrict__ ninv,
                                              const float* __restrict__ embT, const int* __restrict__ nidx,
                                              const float* __restrict__ W,
                                              const float* __restrict__ a_s, const float* __restrict__ a_d,
                                              float* __restrict__ H, float* __restrict__ asn,
                                              float* __restrict__ adn) {
    int lane = threadIdx.x & 63;
    int wid = (blockIdx.x * 256 + threadIdx.x) >> 6;
    int rowbase = __builtin_amdgcn_readfirstlane(wid * 8);
    if (rowbase >= N_NODES) return;
    int c0 = lane, c1 = lane + 64;
    float acc[8][2];
#pragma unroll
    for (int r = 0; r < 8; r++) { acc[r][0] = 0.f; acc[r][1] = 0.f; }
    const float* Ab = A + (size_t)rowbase * KA;
#pragma unroll 4
    for (int k = 0; k < KA; k++) {
        float w0 = W[k * HID + c0];
        float w1 = W[k * HID + c1];
#pragma unroll
        for (int r = 0; r < 8; r++) {
            float a = Ab[r * KA + k];
            acc[r][0] = fmaf(a, w0, acc[r][0]);
            acc[r][1] = fmaf(a, w1, acc[r][1]);
        }
    }
    if constexpr (NRM) {
#pragma unroll
        for (int r = 0; r < 8; r++) {
            float inv = ninv[rowbase + r];
            acc[r][0] *= inv;
            acc[r][1] *= inv;
        }
    }
    if constexpr (KE > 0) {
        int nid[8];
#pragma unroll
        for (int r = 0; r < 8; r++) nid[r] = __builtin_amdgcn_readfirstlane(nidx[rowbase + r]);
#pragma unroll 4
        for (int k2 = 0; k2 < KE; k2++) {
            int k = KA + k2;
            float w0 = W[k * HID + c0];
            float w1 = W[k * HID + c1];
#pragma unroll
            for (int r = 0; r < 8; r++) {
                float a = embT[nid[r] * KE + k2];
                acc[r][0] = fmaf(a, w0, acc[r][0]);
                acc[r][1] = fmaf(a, w1, acc[r][1]);
            }
        }
    }
    float as0 = a_s[c0], as1 = a_s[c1];
    float ad0 = a_d[c0], ad1 = a_d[c1];
#pragma unroll
    for (int r = 0; r < 8; r++) {
        int row = rowbase + r;
        float h0 = acc[r][0], h1 = acc[r][1];
        H[(size_t)row * HID + c0] = h0;
        H[(size_t)row * HID + c1] = h1;
        float ps = h0 * as0 + h1 * as1;
        float pd = h0 * ad0 + h1 * ad1;
#pragma unroll
        for (int o = 32; o; o >>= 1) {
            ps += __shfl_xor(ps, o);
            pd += __shfl_xor(pd, o);
        }
        if (lane == 0) { asn[row] = ps; adn[row] = pd; }
    }
}

// ---------- GAT aggregation: wave per dst node ----------
// Fast path (deg<=64): single gather pass, softmax in registers, channel pass with
// readlane scalar broadcast (SGPR base addressing) unrolled x4.
__global__ __launch_bounds__(256) void k_aggr(const int* __restrict__ rowptr, const int* __restrict__ csr,
                                              const float* __restrict__ asn, const float* __restrict__ adn,
                                              const float* __restrict__ h, const float* __restrict__ bias,
                                              float* __restrict__ out) {
    __shared__ float sh_e[4][64];
    __shared__ int sh_s[4][64];
    int lane = threadIdx.x & 63;
    int w = threadIdx.x >> 6;
    int node = blockIdx.x * 4 + w;
    if (node >= N_NODES) return;
    int st = rowptr[node], en = rowptr[node + 1];
    int deg = en - st;
    float ad = adn[node];
    const float2* h2 = (const float2*)h;
    float2 acc = make_float2(0.f, 0.f);

    if (deg <= 64) {
        int s = 0;
        float l = -1e30f;
        if (lane < deg) {
            s = csr[st + lane];
            l = lrelu02(asn[s] + ad);
        }
        float m = l;
#pragma unroll
        for (int o = 32; o; o >>= 1) m = fmaxf(m, __shfl_xor(m, o));
        float e = (lane < deg) ? __expf(l - m) : 0.f;
        float ssum = e;
#pragma unroll
        for (int o = 32; o; o >>= 1) ssum += __shfl_xor(ssum, o);
        float coef = e / ssum;
        int j = 0;
        for (; j + 4 <= deg; j += 4) {
            int s0 = __builtin_amdgcn_readlane(s, j);
            int s1 = __builtin_amdgcn_readlane(s, j + 1);
            int s2 = __builtin_amdgcn_readlane(s, j + 2);
            int s3 = __builtin_amdgcn_readlane(s, j + 3);
            float c0 = rl_f(coef, j);
            float c1 = rl_f(coef, j + 1);
            float c2 = rl_f(coef, j + 2);
            float c3 = rl_f(coef, j + 3);
            float2 v0 = h2[(size_t)s0 * 64 + lane];
            float2 v1 = h2[(size_t)s1 * 64 + lane];
            float2 v2 = h2[(size_t)s2 * 64 + lane];
            float2 v3 = h2[(size_t)s3 * 64 + lane];
            acc.x = fmaf(c0, v0.x, acc.x); acc.y = fmaf(c0, v0.y, acc.y);
            acc.x = fmaf(c1, v1.x, acc.x); acc.y = fmaf(c1, v1.y, acc.y);
            acc.x = fmaf(c2, v2.x, acc.x); acc.y = fmaf(c2, v2.y, acc.y);
            acc.x = fmaf(c3, v3.x, acc.x); acc.y = fmaf(c3, v3.y, acc.y);
        }
        for (; j < deg; j++) {
            int s0 = __builtin_amdgcn_readlane(s, j);
            float c0 = rl_f(coef, j);
            float2 v0 = h2[(size_t)s0 * 64 + lane];
            acc.x = fmaf(c0, v0.x, acc.x); acc.y = fmaf(c0, v0.y, acc.y);
        }
    } else {
        // general fallback (3-pass, chunked) — degree > 64 is possible only in
        // adversarial inputs; correctness path.
        float m = -1e30f;
        for (int i = st + lane; i < en; i += 64) {
            float l = lrelu02(asn[csr[i]] + ad);
            m = fmaxf(m, l);
        }
#pragma unroll
        for (int o = 32; o; o >>= 1) m = fmaxf(m, __shfl_xor(m, o));
        float ssum = 0.f;
        for (int i = st + lane; i < en; i += 64) {
            float l = lrelu02(asn[csr[i]] + ad);
            ssum += __expf(l - m);
        }
#pragma unroll
        for (int o = 32; o; o >>= 1) ssum += __shfl_xor(ssum, o);
        float inv = 1.f / ssum;
        for (int base = st; base < en; base += 64) {
            int cnt = min(64, en - base);
            if (lane < cnt) {
                int s = csr[base + lane];
                float l = lrelu02(asn[s] + ad);
                sh_e[w][lane] = __expf(l - m) * inv;
                sh_s[w][lane] = s;
            }
            for (int j = 0; j < cnt; j++) {
                float c = sh_e[w][j];
                int s = sh_s[w][j];
                float2 hv = h2[(size_t)s * 64 + lane];
                acc.x = fmaf(c, hv.x, acc.x);
                acc.y = fmaf(c, hv.y, acc.y);
            }
        }
    }
    float2 b = ((const float2*)bias)[lane];
    float2 res;
    res.x = gelu_f(acc.x + b.x);
    res.y = gelu_f(acc.y + b.y);
    ((float2*)out)[(size_t)node * 64 + lane] = res;
}

// ---------- global_add_pool: batch is sorted, register-accumulate per channel ----------
__global__ __launch_bounds__(128) void k_pool(const float* __restrict__ h, const int* __restrict__ batch,
                                              float* __restrict__ g) {
    int c = threadIdx.x;  // 0..127
    int n0 = blockIdx.x * 128;
    if (n0 >= N_NODES) return;
    int n1 = min(n0 + 128, N_NODES);
    int cur = batch[n0];
    float acc = 0.f;
    for (int n = n0; n < n1; n++) {
        int b = batch[n];
        if (b != cur) {
            atomicAdd(&g[cur * HID + c], acc);
            acc = 0.f;
            cur = b;
        }
        acc += h[(size_t)n * HID + c];
    }
    atomicAdd(&g[cur * HID + c], acc);
}

// ---------- final fc + leaky_relu(0.01) ----------
__global__ __launch_bounds__(256) void k_fc(const float* __restrict__ g, const float* __restrict__ fcW,
                                            const float* __restrict__ fcb, float* __restrict__ out) {
    int tid = blockIdx.x * 256 + threadIdx.x;
    if (tid >= NUM_GRAPHS * OUT_DIM) return;
    int gr = tid >> 6;  // OUT_DIM = 64
    int c = tid & 63;
    float acc = fcb[c];
    const float* grow = g + gr * HID;
#pragma unroll 4
    for (int k = 0; k < HID; k++) acc = fmaf(grow[k], fcW[k * OUT_DIM + c], acc);
    out[tid] = acc > 0.f ? acc : 0.01f * acc;
}

extern "C" void kernel_launch(void* const* d_in, const int* in_sizes, int n_in,
                              void* d_out, int out_size, void* d_ws, size_t ws_size,
                              hipStream_t stream) {
    const float* x    = (const float*)d_in[0];
    const int* nidx   = (const int*)d_in[1];
    const int* ei     = (const int*)d_in[2];
    const int* batch  = (const int*)d_in[3];
    const float* emb  = (const float*)d_in[4];
    const float* W1   = (const float*)d_in[5];
    const float* a1s  = (const float*)d_in[6];
    const float* a1d  = (const float*)d_in[7];
    const float* b1   = (const float*)d_in[8];
    const float* W2   = (const float*)d_in[9];
    const float* a2s  = (const float*)d_in[10];
    const float* a2d  = (const float*)d_in[11];
    const float* b2   = (const float*)d_in[12];
    const float* W3   = (const float*)d_in[13];
    const float* a3s  = (const float*)d_in[14];
    const float* a3d  = (const float*)d_in[15];
    const float* b3   = (const float*)d_in[16];
    const float* fcW  = (const float*)d_in[17];
    const float* fcb  = (const float*)d_in[18];
    float* out = (float*)d_out;
    const int* srcA = ei;
    const int* dstA = ei + N_EDGES;

    char* w = (char*)d_ws;
    auto alloc = [&](size_t bytes) -> char* {
        char* p = w;
        w += (bytes + 511) & ~(size_t)511;
        return p;
    };
    float* hA    = (float*)alloc((size_t)N_NODES * HID * 4);   // 25.6 MB
    float* hB    = (float*)alloc((size_t)N_NODES * HID * 4);   // 25.6 MB
    float* asn   = (float*)alloc((size_t)N_NODES * 4);
    float* adn   = (float*)alloc((size_t)N_NODES * 4);
    float* ninv  = (float*)alloc((size_t)N_NODES * 4);
    int* rowptr  = (int*)alloc((size_t)(N_NODES + 1) * 4);
    int* deg     = (int*)alloc((size_t)N_NODES * 4);
    int* fillc   = (int*)alloc((size_t)N_NODES * 4);
    int* bsum    = (int*)alloc(1024);
    int* boff    = (int*)alloc(1024);
    int* csr     = (int*)alloc((size_t)E_TOT * 4);             // 3.4 MB
    float* g     = (float*)alloc((size_t)NUM_GRAPHS * HID * 4);

    hipMemsetAsync(deg, 0, (size_t)N_NODES * 4, stream);
    hipMemsetAsync(fillc, 0, (size_t)N_NODES * 4, stream);
    hipMemsetAsync(g, 0, (size_t)NUM_GRAPHS * HID * 4, stream);

    int nb = (N_NODES + 255) / 256;  // 196 scan blocks
    k_norms<<<(N_NODES + 3) / 4, 256, 0, stream>>>(x, ninv);
    k_deg<<<(N_EDGES + 255) / 256, 256, 0, stream>>>(dstA, deg);
    k_scanA<<<nb, 256, 0, stream>>>(deg, bsum);
    k_scanB<<<1, 256, 0, stream>>>(bsum, boff, nb);
    k_scanC<<<nb, 256, 0, stream>>>(deg, boff, rowptr);
    k_fill<<<(E_TOT + 255) / 256, 256, 0, stream>>>(srcA, dstA, rowptr, fillc, csr);

    int gemmBlocks = (((N_NODES + 7) / 8) + 3) / 4;  // 1563
    int aggrBlocks = (N_NODES + 3) / 4;              // 12500

    k_gemm<IN_DIM, EMB_DIM, true><<<gemmBlocks, 256, 0, stream>>>(x, ninv, emb, nidx, W1, a1s, a1d, hA, asn, adn);
    k_aggr<<<aggrBlocks, 256, 0, stream>>>(rowptr, csr, asn, adn, hA, b1, hB);
    k_gemm<HID, 0, false><<<gemmBlocks, 256, 0, stream>>>(hB, nullptr, nullptr, nullptr, W2, a2s, a2d, hA, asn, adn);
    k_aggr<<<aggrBlocks, 256, 0, stream>>>(rowptr, csr, asn, adn, hA, b2, hB);
    k_gemm<HID, 0, false><<<gemmBlocks, 256, 0, stream>>>(hB, nullptr, nullptr, nullptr, W3, a3s, a3d, hA, asn, adn);
    k_aggr<<<aggrBlocks, 256, 0, stream>>>(rowptr, csr, asn, adn, hA, b3, hB);

    k_pool<<<(N_NODES + 127) / 128, 128, 0, stream>>>(hB, batch, g);
    k_fc<<<(NUM_GRAPHS * OUT_DIM + 255) / 256, 256, 0, stream>>>(g, fcW, fcb, out);
}

// Round 3
// 413.911 us; speedup vs baseline: 1.3674x; 1.3187x over previous
//
#include <hip/hip_runtime.h>

#define N_NODES 50000
#define N_EDGES 800000
#define IN_DIM 128
#define EMB_DIM 64
#define HID 128
#define OUT_DIM 64
#define NUM_GRAPHS 128
#define E_TOT (N_EDGES + N_NODES)
#define K1 (IN_DIM + EMB_DIM)   // 192

typedef __attribute__((ext_vector_type(8))) short bf16x8;
typedef __attribute__((ext_vector_type(4))) float f32x4;

__device__ __forceinline__ float gelu_f(float x) {
    float x3 = x * x * x;
    return 0.5f * x * (1.0f + tanhf(0.7978845608028654f * (x + 0.044715f * x3)));
}
__device__ __forceinline__ float lrelu02(float x) { return x > 0.f ? x : 0.2f * x; }
__device__ __forceinline__ float rl_f(float v, int j) {
    return __int_as_float(__builtin_amdgcn_readlane(__float_as_int(v), j));
}
__device__ __forceinline__ unsigned short f2bf(float f) {  // RNE
    unsigned u = __float_as_uint(f);
    unsigned r = (u + 0x7fffu + ((u >> 16) & 1u)) >> 16;
    return (unsigned short)r;
}
__device__ __forceinline__ unsigned pk2bf(float a, float b) {
    return (unsigned)f2bf(a) | ((unsigned)f2bf(b) << 16);
}

// ---------- prep A for layer 1: Abf[n] = [x[n]/||x[n]|| | emb[nidx[n]]] bf16 [N,192] ----------
__global__ __launch_bounds__(256) void k_prepA(const float* __restrict__ x, const int* __restrict__ nidx,
                                               const float* __restrict__ emb, unsigned* __restrict__ Abu) {
    int lane = threadIdx.x & 63;
    int node = (blockIdx.x * 256 + threadIdx.x) >> 6;
    if (node >= N_NODES) return;
    float2 v = ((const float2*)(x + (size_t)node * IN_DIM))[lane];
    float ss = v.x * v.x + v.y * v.y;
#pragma unroll
    for (int o = 32; o; o >>= 1) ss += __shfl_xor(ss, o);
    float nrm = sqrtf(ss);
    if (nrm == 0.f) nrm = 1e-8f;
    float inv = 1.f / nrm;
    unsigned* row = Abu + (size_t)node * (K1 / 2);
    row[lane] = pk2bf(v.x * inv, v.y * inv);
    int nid = __builtin_amdgcn_readfirstlane(nidx[node]);
    if (lane < 32) {
        float2 e = ((const float2*)(emb + (size_t)nid * EMB_DIM))[lane];
        row[64 + lane] = pk2bf(e.x, e.y);
    }
}

// ---------- prep W^T bf16 padded: Wt[c][k], stride KP = K+8 ----------
__global__ __launch_bounds__(128) void k_prepW(const float* __restrict__ W, unsigned short* __restrict__ Wt,
                                               int K, int KP) {
    int k = blockIdx.x;   // 0..K-1
    int c = threadIdx.x;  // 0..127
    Wt[(size_t)c * KP + k] = f2bf(W[(size_t)k * HID + c]);
}

// ---------- degree histogram over dst ----------
__global__ __launch_bounds__(256) void k_deg(const int* __restrict__ dst, int* __restrict__ deg) {
    int e = blockIdx.x * 256 + threadIdx.x;
    if (e < N_EDGES) atomicAdd(&deg[dst[e]], 1);
}

// ---------- scan A/B/C ----------
__global__ __launch_bounds__(256) void k_scanA(const int* __restrict__ deg, int* __restrict__ bsum) {
    __shared__ int sh[256];
    int i = blockIdx.x * 256 + threadIdx.x;
    int v = (i < N_NODES) ? deg[i] + 1 : 0;
    sh[threadIdx.x] = v;
    __syncthreads();
    for (int o = 128; o; o >>= 1) {
        if (threadIdx.x < o) sh[threadIdx.x] += sh[threadIdx.x + o];
        __syncthreads();
    }
    if (threadIdx.x == 0) bsum[blockIdx.x] = sh[0];
}
__global__ __launch_bounds__(256) void k_scanB(const int* __restrict__ bsum, int* __restrict__ boff, int nb) {
    __shared__ int sh[256];
    int t = threadIdx.x;
    int v = (t < nb) ? bsum[t] : 0;
    sh[t] = v;
    __syncthreads();
    for (int o = 1; o < 256; o <<= 1) {
        int u = (t >= o) ? sh[t - o] : 0;
        __syncthreads();
        sh[t] += u;
        __syncthreads();
    }
    boff[t] = sh[t] - v;
}
__global__ __launch_bounds__(256) void k_scanC(const int* __restrict__ deg, const int* __restrict__ boff,
                                               int* __restrict__ rowptr) {
    __shared__ int sh[256];
    int t = threadIdx.x;
    int i = blockIdx.x * 256 + t;
    int v = (i < N_NODES) ? deg[i] + 1 : 0;
    sh[t] = v;
    __syncthreads();
    for (int o = 1; o < 256; o <<= 1) {
        int u = (t >= o) ? sh[t - o] : 0;
        __syncthreads();
        sh[t] += u;
        __syncthreads();
    }
    int excl = sh[t] - v + boff[blockIdx.x];
    if (i < N_NODES) rowptr[i] = excl;
    if (i == N_NODES - 1) rowptr[N_NODES] = excl + v;
}

// ---------- fill CSR ----------
__global__ __launch_bounds__(256) void k_fill(const int* __restrict__ src, const int* __restrict__ dst,
                                              const int* __restrict__ rowptr, int* __restrict__ fillc,
                                              int* __restrict__ csr) {
    int t = blockIdx.x * 256 + threadIdx.x;
    if (t >= E_TOT) return;
    int s, d;
    if (t < N_EDGES) { s = src[t]; d = dst[t]; }
    else { s = d = t - N_EDGES; }
    int p = rowptr[d] + atomicAdd(&fillc[d], 1);
    csr[p] = s;
}

// ---------- MFMA GEMM: Hbf[N,128] = Abf[N,K] @ W, asn/adn from fp32 acc ----------
// per wave: 16 rows x 128 cols via 8 tiles of mfma_f32_16x16x32_bf16.
// A-frag: A[m=lane&15][k = quad*8+j]  (verified layout)
// B-frag: W^T[n=lane&15][k = quad*8+j] from LDS (padded stride KP)
// C/D:    col = lane&15, row = quad*4 + reg
template <int K>
__global__ __launch_bounds__(256) void k_mgemm(const unsigned short* __restrict__ Abf,
                                               const unsigned short* __restrict__ WtP,
                                               const float* __restrict__ a_s, const float* __restrict__ a_d,
                                               unsigned short* __restrict__ Hbf,
                                               float* __restrict__ asn, float* __restrict__ adn) {
    constexpr int KP = K + 8;
    __shared__ __align__(16) unsigned short Wl[128 * KP];
    {
        const uint4* gsrc = (const uint4*)WtP;
        uint4* ldst = (uint4*)Wl;
        const int nchunk = 128 * KP * 2 / 16;
        for (int i = threadIdx.x; i < nchunk; i += 256) ldst[i] = gsrc[i];
    }
    __syncthreads();
    int lane = threadIdx.x & 63;
    int wv = threadIdx.x >> 6;
    int rowbase = blockIdx.x * 64 + wv * 16;
    if (rowbase >= N_NODES) return;
    int l15 = lane & 15, quad = lane >> 4;

    f32x4 acc[8];
#pragma unroll
    for (int t = 0; t < 8; t++) acc[t] = (f32x4){0.f, 0.f, 0.f, 0.f};

    const unsigned short* Abase = Abf + (size_t)(rowbase + l15) * K + quad * 8;
#pragma unroll
    for (int k0 = 0; k0 < K; k0 += 32) {
        bf16x8 af = *(const bf16x8*)(Abase + k0);
#pragma unroll
        for (int t = 0; t < 8; t++) {
            bf16x8 bf = *(const bf16x8*)(&Wl[(t * 16 + l15) * KP + k0 + quad * 8]);
            acc[t] = __builtin_amdgcn_mfma_f32_16x16x32_bf16(af, bf, acc[t], 0, 0, 0);
        }
    }
    // epilogue: store bf16 H, reduce asn/adn per row
    float asc[8], adc[8];
#pragma unroll
    for (int t = 0; t < 8; t++) { asc[t] = a_s[t * 16 + l15]; adc[t] = a_d[t * 16 + l15]; }
#pragma unroll
    for (int r = 0; r < 4; r++) {
        int row = rowbase + quad * 4 + r;
        float ps = 0.f, pd = 0.f;
#pragma unroll
        for (int t = 0; t < 8; t++) {
            float v = acc[t][r];
            Hbf[(size_t)row * HID + t * 16 + l15] = f2bf(v);
            ps = fmaf(v, asc[t], ps);
            pd = fmaf(v, adc[t], pd);
        }
#pragma unroll
        for (int o = 1; o < 16; o <<= 1) {
            ps += __shfl_xor(ps, o);
            pd += __shfl_xor(pd, o);
        }
        if (l15 == 0) { asn[row] = ps; adn[row] = pd; }
    }
}

// ---------- GAT aggregation: wave per dst node, bf16 gather ----------
template <bool OUT32>
__global__ __launch_bounds__(256) void k_aggr(const int* __restrict__ rowptr, const int* __restrict__ csr,
                                              const float* __restrict__ asn, const float* __restrict__ adn,
                                              const unsigned short* __restrict__ hbf,
                                              const float* __restrict__ bias, void* __restrict__ outp) {
    __shared__ float sh_e[4][64];
    __shared__ int sh_s[4][64];
    int lane = threadIdx.x & 63;
    int w = threadIdx.x >> 6;
    int node = blockIdx.x * 4 + w;
    if (node >= N_NODES) return;
    int st = rowptr[node], en = rowptr[node + 1];
    int deg = en - st;
    float ad = adn[node];
    const unsigned* hu = (const unsigned*)hbf;
    float2 acc = make_float2(0.f, 0.f);

    if (deg <= 64) {
        int s = 0;
        float l = -1e30f;
        if (lane < deg) {
            s = csr[st + lane];
            l = lrelu02(asn[s] + ad);
        }
        float m = l;
#pragma unroll
        for (int o = 32; o; o >>= 1) m = fmaxf(m, __shfl_xor(m, o));
        float e = (lane < deg) ? __expf(l - m) : 0.f;
        float ssum = e;
#pragma unroll
        for (int o = 32; o; o >>= 1) ssum += __shfl_xor(ssum, o);
        float coef = e / ssum;
        int j = 0;
        for (; j + 4 <= deg; j += 4) {
            int s0 = __builtin_amdgcn_readlane(s, j);
            int s1 = __builtin_amdgcn_readlane(s, j + 1);
            int s2 = __builtin_amdgcn_readlane(s, j + 2);
            int s3 = __builtin_amdgcn_readlane(s, j + 3);
            float c0 = rl_f(coef, j), c1 = rl_f(coef, j + 1);
            float c2 = rl_f(coef, j + 2), c3 = rl_f(coef, j + 3);
            unsigned v0 = hu[(size_t)s0 * 64 + lane];
            unsigned v1 = hu[(size_t)s1 * 64 + lane];
            unsigned v2 = hu[(size_t)s2 * 64 + lane];
            unsigned v3 = hu[(size_t)s3 * 64 + lane];
            acc.x = fmaf(c0, __int_as_float(v0 << 16), acc.x);
            acc.y = fmaf(c0, __int_as_float(v0 & 0xffff0000u), acc.y);
            acc.x = fmaf(c1, __int_as_float(v1 << 16), acc.x);
            acc.y = fmaf(c1, __int_as_float(v1 & 0xffff0000u), acc.y);
            acc.x = fmaf(c2, __int_as_float(v2 << 16), acc.x);
            acc.y = fmaf(c2, __int_as_float(v2 & 0xffff0000u), acc.y);
            acc.x = fmaf(c3, __int_as_float(v3 << 16), acc.x);
            acc.y = fmaf(c3, __int_as_float(v3 & 0xffff0000u), acc.y);
        }
        for (; j < deg; j++) {
            int s0 = __builtin_amdgcn_readlane(s, j);
            float c0 = rl_f(coef, j);
            unsigned v0 = hu[(size_t)s0 * 64 + lane];
            acc.x = fmaf(c0, __int_as_float(v0 << 16), acc.x);
            acc.y = fmaf(c0, __int_as_float(v0 & 0xffff0000u), acc.y);
        }
    } else {
        float m = -1e30f;
        for (int i = st + lane; i < en; i += 64) {
            float l = lrelu02(asn[csr[i]] + ad);
            m = fmaxf(m, l);
        }
#pragma unroll
        for (int o = 32; o; o >>= 1) m = fmaxf(m, __shfl_xor(m, o));
        float ssum = 0.f;
        for (int i = st + lane; i < en; i += 64) {
            float l = lrelu02(asn[csr[i]] + ad);
            ssum += __expf(l - m);
        }
#pragma unroll
        for (int o = 32; o; o >>= 1) ssum += __shfl_xor(ssum, o);
        float inv = 1.f / ssum;
        for (int base = st; base < en; base += 64) {
            int cnt = min(64, en - base);
            if (lane < cnt) {
                int s = csr[base + lane];
                float l = lrelu02(asn[s] + ad);
                sh_e[w][lane] = __expf(l - m) * inv;
                sh_s[w][lane] = s;
            }
            for (int j = 0; j < cnt; j++) {
                float c = sh_e[w][j];
                int s = sh_s[w][j];
                unsigned v0 = hu[(size_t)s * 64 + lane];
                acc.x = fmaf(c, __int_as_float(v0 << 16), acc.x);
                acc.y = fmaf(c, __int_as_float(v0 & 0xffff0000u), acc.y);
            }
        }
    }
    float2 b = ((const float2*)bias)[lane];
    float rx = gelu_f(acc.x + b.x);
    float ry = gelu_f(acc.y + b.y);
    if constexpr (OUT32) {
        ((float2*)outp)[(size_t)node * 64 + lane] = make_float2(rx, ry);
    } else {
        ((unsigned*)outp)[(size_t)node * 64 + lane] = pk2bf(rx, ry);
    }
}

// ---------- global_add_pool (batch sorted) ----------
__global__ __launch_bounds__(128) void k_pool(const float* __restrict__ h, const int* __restrict__ batch,
                                              float* __restrict__ g) {
    int c = threadIdx.x;
    int n0 = blockIdx.x * 128;
    if (n0 >= N_NODES) return;
    int n1 = min(n0 + 128, N_NODES);
    int cur = batch[n0];
    float acc = 0.f;
    for (int n = n0; n < n1; n++) {
        int b = batch[n];
        if (b != cur) {
            atomicAdd(&g[cur * HID + c], acc);
            acc = 0.f;
            cur = b;
        }
        acc += h[(size_t)n * HID + c];
    }
    atomicAdd(&g[cur * HID + c], acc);
}

// ---------- final fc + leaky_relu(0.01) ----------
__global__ __launch_bounds__(256) void k_fc(const float* __restrict__ g, const float* __restrict__ fcW,
                                            const float* __restrict__ fcb, float* __restrict__ out) {
    int tid = blockIdx.x * 256 + threadIdx.x;
    if (tid >= NUM_GRAPHS * OUT_DIM) return;
    int gr = tid >> 6;
    int c = tid & 63;
    float acc = fcb[c];
    const float* grow = g + gr * HID;
#pragma unroll 4
    for (int k = 0; k < HID; k++) acc = fmaf(grow[k], fcW[k * OUT_DIM + c], acc);
    out[tid] = acc > 0.f ? acc : 0.01f * acc;
}

extern "C" void kernel_launch(void* const* d_in, const int* in_sizes, int n_in,
                              void* d_out, int out_size, void* d_ws, size_t ws_size,
                              hipStream_t stream) {
    const float* x    = (const float*)d_in[0];
    const int* nidx   = (const int*)d_in[1];
    const int* ei     = (const int*)d_in[2];
    const int* batch  = (const int*)d_in[3];
    const float* emb  = (const float*)d_in[4];
    const float* W1   = (const float*)d_in[5];
    const float* a1s  = (const float*)d_in[6];
    const float* a1d  = (const float*)d_in[7];
    const float* b1   = (const float*)d_in[8];
    const float* W2   = (const float*)d_in[9];
    const float* a2s  = (const float*)d_in[10];
    const float* a2d  = (const float*)d_in[11];
    const float* b2   = (const float*)d_in[12];
    const float* W3   = (const float*)d_in[13];
    const float* a3s  = (const float*)d_in[14];
    const float* a3d  = (const float*)d_in[15];
    const float* b3   = (const float*)d_in[16];
    const float* fcW  = (const float*)d_in[17];
    const float* fcb  = (const float*)d_in[18];
    float* out = (float*)d_out;
    const int* srcA = ei;
    const int* dstA = ei + N_EDGES;

    char* w = (char*)d_ws;
    auto alloc = [&](size_t bytes) -> char* {
        char* p = w;
        w += (bytes + 511) & ~(size_t)511;
        return p;
    };
    // region0: Abf [N,192] bf16 (19.2MB) during prep+GEMM1; later h3f fp32 [N,128] (25.6MB)
    char* region0 = alloc((size_t)N_NODES * HID * 4);
    unsigned* Abu = (unsigned*)region0;
    float* h3f    = (float*)region0;
    unsigned short* hLin = (unsigned short*)alloc((size_t)N_NODES * HID * 2);  // GEMM out, gather src
    unsigned short* hAct = (unsigned short*)alloc((size_t)N_NODES * HID * 2);  // aggr out, GEMM in
    float* asn   = (float*)alloc((size_t)N_NODES * 4);
    float* adn   = (float*)alloc((size_t)N_NODES * 4);
    int* rowptr  = (int*)alloc((size_t)(N_NODES + 1) * 4);
    int* deg     = (int*)alloc((size_t)N_NODES * 4);
    int* fillc   = (int*)alloc((size_t)N_NODES * 4);
    int* bsum    = (int*)alloc(1024);
    int* boff    = (int*)alloc(1024);
    int* csr     = (int*)alloc((size_t)E_TOT * 4);
    float* g     = (float*)alloc((size_t)NUM_GRAPHS * HID * 4);
    unsigned short* Wt1 = (unsigned short*)alloc((size_t)HID * (K1 + 8) * 2);
    unsigned short* Wt2 = (unsigned short*)alloc((size_t)HID * (HID + 8) * 2);
    unsigned short* Wt3 = (unsigned short*)alloc((size_t)HID * (HID + 8) * 2);

    hipMemsetAsync(deg, 0, (size_t)N_NODES * 4, stream);
    hipMemsetAsync(fillc, 0, (size_t)N_NODES * 4, stream);
    hipMemsetAsync(g, 0, (size_t)NUM_GRAPHS * HID * 4, stream);

    int nb = (N_NODES + 255) / 256;
    k_prepW<<<K1, 128, 0, stream>>>(W1, Wt1, K1, K1 + 8);
    k_prepW<<<HID, 128, 0, stream>>>(W2, Wt2, HID, HID + 8);
    k_prepW<<<HID, 128, 0, stream>>>(W3, Wt3, HID, HID + 8);
    k_prepA<<<(N_NODES + 3) / 4, 256, 0, stream>>>(x, nidx, emb, Abu);
    k_deg<<<(N_EDGES + 255) / 256, 256, 0, stream>>>(dstA, deg);
    k_scanA<<<nb, 256, 0, stream>>>(deg, bsum);
    k_scanB<<<1, 256, 0, stream>>>(bsum, boff, nb);
    k_scanC<<<nb, 256, 0, stream>>>(deg, boff, rowptr);
    k_fill<<<(E_TOT + 255) / 256, 256, 0, stream>>>(srcA, dstA, rowptr, fillc, csr);

    int gemmBlocks = (N_NODES + 63) / 64;  // 782
    int aggrBlocks = (N_NODES + 3) / 4;    // 12500

    k_mgemm<K1><<<gemmBlocks, 256, 0, stream>>>((const unsigned short*)Abu, Wt1, a1s, a1d, hLin, asn, adn);
    k_aggr<false><<<aggrBlocks, 256, 0, stream>>>(rowptr, csr, asn, adn, hLin, b1, hAct);
    k_mgemm<HID><<<gemmBlocks, 256, 0, stream>>>(hAct, Wt2, a2s, a2d, hLin, asn, adn);
    k_aggr<false><<<aggrBlocks, 256, 0, stream>>>(rowptr, csr, asn, adn, hLin, b2, hAct);
    k_mgemm<HID><<<gemmBlocks, 256, 0, stream>>>(hAct, Wt3, a3s, a3d, hLin, asn, adn);
    k_aggr<true><<<aggrBlocks, 256, 0, stream>>>(rowptr, csr, asn, adn, hLin, b3, h3f);

    k_pool<<<(N_NODES + 127) / 128, 128, 0, stream>>>(h3f, batch, g);
    k_fc<<<(NUM_GRAPHS * OUT_DIM + 255) / 256, 256, 0, stream>>>(g, fcW, fcb, out);
}

// Round 4
// 372.637 us; speedup vs baseline: 1.5189x; 1.1108x over previous
//
#include <hip/hip_runtime.h>

#define N_NODES 50000
#define N_EDGES 800000
#define IN_DIM 128
#define EMB_DIM 64
#define HID 128
#define OUT_DIM 64
#define NUM_GRAPHS 128
#define E_TOT (N_EDGES + N_NODES)
#define K1 (IN_DIM + EMB_DIM)   // 192
#define NB 391                   // ceil(N_NODES/128) buckets of 128 dst nodes
#define EPT 16
#define EPB (256 * EPT)          // 4096 edges per passA block

typedef __attribute__((ext_vector_type(8))) short bf16x8;
typedef __attribute__((ext_vector_type(4))) float f32x4;

__device__ __forceinline__ float gelu_f(float x) {
    float x3 = x * x * x;
    return 0.5f * x * (1.0f + tanhf(0.7978845608028654f * (x + 0.044715f * x3)));
}
__device__ __forceinline__ float lrelu02(float x) { return x > 0.f ? x : 0.2f * x; }
__device__ __forceinline__ float rl_f(float v, int j) {
    return __int_as_float(__builtin_amdgcn_readlane(__float_as_int(v), j));
}
__device__ __forceinline__ unsigned short f2bf(float f) {  // RNE
    unsigned u = __float_as_uint(f);
    unsigned r = (u + 0x7fffu + ((u >> 16) & 1u)) >> 16;
    return (unsigned short)r;
}
__device__ __forceinline__ unsigned pk2bf(float a, float b) {
    return (unsigned)f2bf(a) | ((unsigned)f2bf(b) << 16);
}

// ---------- prep A for layer 1: Abf[n] = [x[n]/||x[n]|| | emb[nidx[n]]] bf16 [N,192] ----------
__global__ __launch_bounds__(256) void k_prepA(const float* __restrict__ x, const int* __restrict__ nidx,
                                               const float* __restrict__ emb, unsigned* __restrict__ Abu) {
    int lane = threadIdx.x & 63;
    int node = (blockIdx.x * 256 + threadIdx.x) >> 6;
    if (node >= N_NODES) return;
    float2 v = ((const float2*)(x + (size_t)node * IN_DIM))[lane];
    float ss = v.x * v.x + v.y * v.y;
#pragma unroll
    for (int o = 32; o; o >>= 1) ss += __shfl_xor(ss, o);
    float nrm = sqrtf(ss);
    if (nrm == 0.f) nrm = 1e-8f;
    float inv = 1.f / nrm;
    unsigned* row = Abu + (size_t)node * (K1 / 2);
    row[lane] = pk2bf(v.x * inv, v.y * inv);
    int nid = __builtin_amdgcn_readfirstlane(nidx[node]);
    if (lane < 32) {
        float2 e = ((const float2*)(emb + (size_t)nid * EMB_DIM))[lane];
        row[64 + lane] = pk2bf(e.x, e.y);
    }
}

// ---------- prep W^T bf16 padded: Wt[c][k], stride KP = K+8 ----------
__global__ __launch_bounds__(128) void k_prepW(const float* __restrict__ W, unsigned short* __restrict__ Wt,
                                               int K, int KP) {
    int k = blockIdx.x;
    int c = threadIdx.x;
    Wt[(size_t)c * KP + k] = f2bf(W[(size_t)k * HID + c]);
}

// ---------- bucket histogram (LDS-aggregated) ----------
__global__ __launch_bounds__(256) void k_bhist(const int* __restrict__ dst, int* __restrict__ bcnt) {
    __shared__ int h[NB];
    for (int i = threadIdx.x; i < NB; i += 256) h[i] = 0;
    __syncthreads();
    for (int e = blockIdx.x * 256 + threadIdx.x; e < N_EDGES; e += gridDim.x * 256)
        atomicAdd(&h[dst[e] >> 7], 1);
    __syncthreads();
    for (int i = threadIdx.x; i < NB; i += 256)
        if (h[i]) atomicAdd(&bcnt[i], h[i]);
}

// ---------- scan bucket counts -> boff[NB+1]; also rowptr[N]=E_TOT ----------
__global__ __launch_bounds__(512) void k_bscan(const int* __restrict__ bcnt, int* __restrict__ boff,
                                               int* __restrict__ rowptr) {
    __shared__ int sh[512];
    int t = threadIdx.x;
    int v = (t < NB) ? bcnt[t] : 0;
    sh[t] = v;
    __syncthreads();
    for (int o = 1; o < 512; o <<= 1) {
        int u = (t >= o) ? sh[t - o] : 0;
        __syncthreads();
        sh[t] += u;
        __syncthreads();
    }
    if (t < NB) boff[t] = sh[t] - v;
    if (t == NB - 1) boff[NB] = sh[t];
    if (t == 0) rowptr[N_NODES] = E_TOT;
}

// ---------- pass A: partition edges into bucket-major array (4B packed: src | dstlow<<16) ----------
__global__ __launch_bounds__(256) void k_passA(const int* __restrict__ src, const int* __restrict__ dst,
                                               const int* __restrict__ boff, int* __restrict__ bfill,
                                               unsigned* __restrict__ barr) {
    __shared__ int h[NB];
    __shared__ int base[NB];
    for (int i = threadIdx.x; i < NB; i += 256) h[i] = 0;
    __syncthreads();
    int e0 = blockIdx.x * EPB;
    int tag[EPT];
#pragma unroll
    for (int i = 0; i < EPT; i++) {
        int e = e0 + i * 256 + threadIdx.x;
        tag[i] = -1;
        if (e < N_EDGES) {
            int b = dst[e] >> 7;
            int r = atomicAdd(&h[b], 1);  // rank within (block,bucket); r < 4096
            tag[i] = (b << 12) | r;
        }
    }
    __syncthreads();
    for (int i = threadIdx.x; i < NB; i += 256)
        base[i] = h[i] ? atomicAdd(&bfill[i], h[i]) : 0;
    __syncthreads();
#pragma unroll
    for (int i = 0; i < EPT; i++) {
        if (tag[i] >= 0) {
            int e = e0 + i * 256 + threadIdx.x;
            int b = tag[i] >> 12, r = tag[i] & 0xfff;
            unsigned s = (unsigned)src[e];
            unsigned dl = (unsigned)(dst[e] & 127);
            barr[boff[b] + base[b] + r] = s | (dl << 16);  // src fits 16 bits (N<65536)
        }
    }
}

// ---------- pass B: per bucket, build rowptr + csr (self loop at slot 0) ----------
__global__ __launch_bounds__(256) void k_passB(const unsigned* __restrict__ barr, const int* __restrict__ boff,
                                               int* __restrict__ rowptr, int* __restrict__ csr) {
    __shared__ int dcnt[128];
    __shared__ int dsum[128];
    __shared__ int locOff[128];
    int b = blockIdx.x;
    int t = threadIdx.x;
    int n0 = b << 7;
    int cnt = min(128, N_NODES - n0);
    int eb = boff[b], ee = boff[b + 1];
    if (t < 128) dcnt[t] = 0;
    __syncthreads();
    for (int i = eb + t; i < ee; i += 256) atomicAdd(&dcnt[barr[i] >> 16], 1);
    __syncthreads();
    int v = 0;
    if (t < 128) {
        v = (t < cnt) ? dcnt[t] + 1 : 0;  // +1 self loop
        dsum[t] = v;
    }
    __syncthreads();
    for (int o = 1; o < 128; o <<= 1) {
        int u = (t >= o && t < 128) ? dsum[t - o] : 0;
        __syncthreads();
        if (t < 128) dsum[t] += u;
        __syncthreads();
    }
    int csrBase = eb + n0;  // edges before bucket + self loops before bucket
    if (t < 128) {
        locOff[t] = dsum[t] - v;
        dcnt[t] = 0;
    }
    if (t < cnt) {
        int loc = dsum[t] - v;
        rowptr[n0 + t] = csrBase + loc;
        csr[csrBase + loc] = n0 + t;  // self loop
    }
    __syncthreads();
    for (int i = eb + t; i < ee; i += 256) {
        unsigned vv = barr[i];
        int dl = vv >> 16;
        int s = (int)(vv & 0xffffu);
        int k = atomicAdd(&dcnt[dl], 1);
        csr[csrBase + locOff[dl] + 1 + k] = s;
    }
}

// ---------- MFMA GEMM: Hbf[N,128] = Abf[N,K] @ W, asn/adn from fp32 acc ----------
template <int K>
__global__ __launch_bounds__(256) void k_mgemm(const unsigned short* __restrict__ Abf,
                                               const unsigned short* __restrict__ WtP,
                                               const float* __restrict__ a_s, const float* __restrict__ a_d,
                                               unsigned short* __restrict__ Hbf,
                                               float* __restrict__ asn, float* __restrict__ adn) {
    constexpr int KP = K + 8;
    __shared__ __align__(16) unsigned short Wl[128 * KP];
    {
        const uint4* gsrc = (const uint4*)WtP;
        uint4* ldst = (uint4*)Wl;
        const int nchunk = 128 * KP * 2 / 16;
        for (int i = threadIdx.x; i < nchunk; i += 256) ldst[i] = gsrc[i];
    }
    __syncthreads();
    int lane = threadIdx.x & 63;
    int wv = threadIdx.x >> 6;
    int rowbase = blockIdx.x * 64 + wv * 16;
    if (rowbase >= N_NODES) return;
    int l15 = lane & 15, quad = lane >> 4;

    f32x4 acc[8];
#pragma unroll
    for (int t = 0; t < 8; t++) acc[t] = (f32x4){0.f, 0.f, 0.f, 0.f};

    const unsigned short* Abase = Abf + (size_t)(rowbase + l15) * K + quad * 8;
#pragma unroll
    for (int k0 = 0; k0 < K; k0 += 32) {
        bf16x8 af = *(const bf16x8*)(Abase + k0);
#pragma unroll
        for (int t = 0; t < 8; t++) {
            bf16x8 bf = *(const bf16x8*)(&Wl[(t * 16 + l15) * KP + k0 + quad * 8]);
            acc[t] = __builtin_amdgcn_mfma_f32_16x16x32_bf16(af, bf, acc[t], 0, 0, 0);
        }
    }
    float asc[8], adc[8];
#pragma unroll
    for (int t = 0; t < 8; t++) { asc[t] = a_s[t * 16 + l15]; adc[t] = a_d[t * 16 + l15]; }
#pragma unroll
    for (int r = 0; r < 4; r++) {
        int row = rowbase + quad * 4 + r;
        float ps = 0.f, pd = 0.f;
#pragma unroll
        for (int t = 0; t < 8; t++) {
            float v = acc[t][r];
            Hbf[(size_t)row * HID + t * 16 + l15] = f2bf(v);
            ps = fmaf(v, asc[t], ps);
            pd = fmaf(v, adc[t], pd);
        }
#pragma unroll
        for (int o = 1; o < 16; o <<= 1) {
            ps += __shfl_xor(ps, o);
            pd += __shfl_xor(pd, o);
        }
        if (l15 == 0) { asn[row] = ps; adn[row] = pd; }
    }
}

// ---------- GAT aggregation: wave per dst node, bf16 gather ----------
template <bool OUT32>
__global__ __launch_bounds__(256) void k_aggr(const int* __restrict__ rowptr, const int* __restrict__ csr,
                                              const float* __restrict__ asn, const float* __restrict__ adn,
                                              const unsigned short* __restrict__ hbf,
                                              const float* __restrict__ bias, void* __restrict__ outp) {
    __shared__ float sh_e[4][64];
    __shared__ int sh_s[4][64];
    int lane = threadIdx.x & 63;
    int w = threadIdx.x >> 6;
    int node = blockIdx.x * 4 + w;
    if (node >= N_NODES) return;
    int st = rowptr[node], en = rowptr[node + 1];
    int deg = en - st;
    float ad = adn[node];
    const unsigned* hu = (const unsigned*)hbf;
    float2 acc = make_float2(0.f, 0.f);

    if (deg <= 64) {
        int s = 0;
        float l = -1e30f;
        if (lane < deg) {
            s = csr[st + lane];
            l = lrelu02(asn[s] + ad);
        }
        float m = l;
#pragma unroll
        for (int o = 32; o; o >>= 1) m = fmaxf(m, __shfl_xor(m, o));
        float e = (lane < deg) ? __expf(l - m) : 0.f;
        float ssum = e;
#pragma unroll
        for (int o = 32; o; o >>= 1) ssum += __shfl_xor(ssum, o);
        float coef = e / ssum;
        int j = 0;
        for (; j + 4 <= deg; j += 4) {
            int s0 = __builtin_amdgcn_readlane(s, j);
            int s1 = __builtin_amdgcn_readlane(s, j + 1);
            int s2 = __builtin_amdgcn_readlane(s, j + 2);
            int s3 = __builtin_amdgcn_readlane(s, j + 3);
            float c0 = rl_f(coef, j), c1 = rl_f(coef, j + 1);
            float c2 = rl_f(coef, j + 2), c3 = rl_f(coef, j + 3);
            unsigned v0 = hu[(size_t)s0 * 64 + lane];
            unsigned v1 = hu[(size_t)s1 * 64 + lane];
            unsigned v2 = hu[(size_t)s2 * 64 + lane];
            unsigned v3 = hu[(size_t)s3 * 64 + lane];
            acc.x = fmaf(c0, __int_as_float(v0 << 16), acc.x);
            acc.y = fmaf(c0, __int_as_float(v0 & 0xffff0000u), acc.y);
            acc.x = fmaf(c1, __int_as_float(v1 << 16), acc.x);
            acc.y = fmaf(c1, __int_as_float(v1 & 0xffff0000u), acc.y);
            acc.x = fmaf(c2, __int_as_float(v2 << 16), acc.x);
            acc.y = fmaf(c2, __int_as_float(v2 & 0xffff0000u), acc.y);
            acc.x = fmaf(c3, __int_as_float(v3 << 16), acc.x);
            acc.y = fmaf(c3, __int_as_float(v3 & 0xffff0000u), acc.y);
        }
        for (; j < deg; j++) {
            int s0 = __builtin_amdgcn_readlane(s, j);
            float c0 = rl_f(coef, j);
            unsigned v0 = hu[(size_t)s0 * 64 + lane];
            acc.x = fmaf(c0, __int_as_float(v0 << 16), acc.x);
            acc.y = fmaf(c0, __int_as_float(v0 & 0xffff0000u), acc.y);
        }
    } else {
        float m = -1e30f;
        for (int i = st + lane; i < en; i += 64) {
            float l = lrelu02(asn[csr[i]] + ad);
            m = fmaxf(m, l);
        }
#pragma unroll
        for (int o = 32; o; o >>= 1) m = fmaxf(m, __shfl_xor(m, o));
        float ssum = 0.f;
        for (int i = st + lane; i < en; i += 64) {
            float l = lrelu02(asn[csr[i]] + ad);
            ssum += __expf(l - m);
        }
#pragma unroll
        for (int o = 32; o; o >>= 1) ssum += __shfl_xor(ssum, o);
        float inv = 1.f / ssum;
        for (int base = st; base < en; base += 64) {
            int cnt = min(64, en - base);
            if (lane < cnt) {
                int s = csr[base + lane];
                float l = lrelu02(asn[s] + ad);
                sh_e[w][lane] = __expf(l - m) * inv;
                sh_s[w][lane] = s;
            }
            for (int j = 0; j < cnt; j++) {
                float c = sh_e[w][j];
                int s = sh_s[w][j];
                unsigned v0 = hu[(size_t)s * 64 + lane];
                acc.x = fmaf(c, __int_as_float(v0 << 16), acc.x);
                acc.y = fmaf(c, __int_as_float(v0 & 0xffff0000u), acc.y);
            }
        }
    }
    float2 b = ((const float2*)bias)[lane];
    float rx = gelu_f(acc.x + b.x);
    float ry = gelu_f(acc.y + b.y);
    if constexpr (OUT32) {
        ((float2*)outp)[(size_t)node * 64 + lane] = make_float2(rx, ry);
    } else {
        ((unsigned*)outp)[(size_t)node * 64 + lane] = pk2bf(rx, ry);
    }
}

// ---------- global_add_pool (batch sorted) ----------
__global__ __launch_bounds__(128) void k_pool(const float* __restrict__ h, const int* __restrict__ batch,
                                              float* __restrict__ g) {
    int c = threadIdx.x;
    int n0 = blockIdx.x * 128;
    if (n0 >= N_NODES) return;
    int n1 = min(n0 + 128, N_NODES);
    int cur = batch[n0];
    float acc = 0.f;
    for (int n = n0; n < n1; n++) {
        int b = batch[n];
        if (b != cur) {
            atomicAdd(&g[cur * HID + c], acc);
            acc = 0.f;
            cur = b;
        }
        acc += h[(size_t)n * HID + c];
    }
    atomicAdd(&g[cur * HID + c], acc);
}

// ---------- final fc + leaky_relu(0.01) ----------
__global__ __launch_bounds__(256) void k_fc(const float* __restrict__ g, const float* __restrict__ fcW,
                                            const float* __restrict__ fcb, float* __restrict__ out) {
    int tid = blockIdx.x * 256 + threadIdx.x;
    if (tid >= NUM_GRAPHS * OUT_DIM) return;
    int gr = tid >> 6;
    int c = tid & 63;
    float acc = fcb[c];
    const float* grow = g + gr * HID;
#pragma unroll 4
    for (int k = 0; k < HID; k++) acc = fmaf(grow[k], fcW[k * OUT_DIM + c], acc);
    out[tid] = acc > 0.f ? acc : 0.01f * acc;
}

extern "C" void kernel_launch(void* const* d_in, const int* in_sizes, int n_in,
                              void* d_out, int out_size, void* d_ws, size_t ws_size,
                              hipStream_t stream) {
    const float* x    = (const float*)d_in[0];
    const int* nidx   = (const int*)d_in[1];
    const int* ei     = (const int*)d_in[2];
    const int* batch  = (const int*)d_in[3];
    const float* emb  = (const float*)d_in[4];
    const float* W1   = (const float*)d_in[5];
    const float* a1s  = (const float*)d_in[6];
    const float* a1d  = (const float*)d_in[7];
    const float* b1   = (const float*)d_in[8];
    const float* W2   = (const float*)d_in[9];
    const float* a2s  = (const float*)d_in[10];
    const float* a2d  = (const float*)d_in[11];
    const float* b2   = (const float*)d_in[12];
    const float* W3   = (const float*)d_in[13];
    const float* a3s  = (const float*)d_in[14];
    const float* a3d  = (const float*)d_in[15];
    const float* b3   = (const float*)d_in[16];
    const float* fcW  = (const float*)d_in[17];
    const float* fcb  = (const float*)d_in[18];
    float* out = (float*)d_out;
    const int* srcA = ei;
    const int* dstA = ei + N_EDGES;

    char* w = (char*)d_ws;
    auto alloc = [&](size_t bytes) -> char* {
        char* p = w;
        w += (bytes + 511) & ~(size_t)511;
        return p;
    };
    // region0: Abf [N,192] bf16 during prep+GEMM1; later h3f fp32 [N,128]
    char* region0 = alloc((size_t)N_NODES * HID * 4);
    unsigned* Abu = (unsigned*)region0;
    float* h3f    = (float*)region0;
    unsigned short* hLin = (unsigned short*)alloc((size_t)N_NODES * HID * 2);
    unsigned short* hAct = (unsigned short*)alloc((size_t)N_NODES * HID * 2);
    float* asn   = (float*)alloc((size_t)N_NODES * 4);
    float* adn   = (float*)alloc((size_t)N_NODES * 4);
    int* rowptr  = (int*)alloc((size_t)(N_NODES + 1) * 4);
    int* bcnt    = (int*)alloc((size_t)NB * 4);
    int* boff    = (int*)alloc((size_t)(NB + 1) * 4);
    int* bfill   = (int*)alloc((size_t)NB * 4);
    unsigned* barr = (unsigned*)alloc((size_t)N_EDGES * 4);   // 3.2 MB bucket-major edges
    int* csr     = (int*)alloc((size_t)E_TOT * 4);
    float* g     = (float*)alloc((size_t)NUM_GRAPHS * HID * 4);
    unsigned short* Wt1 = (unsigned short*)alloc((size_t)HID * (K1 + 8) * 2);
    unsigned short* Wt2 = (unsigned short*)alloc((size_t)HID * (HID + 8) * 2);
    unsigned short* Wt3 = (unsigned short*)alloc((size_t)HID * (HID + 8) * 2);

    hipMemsetAsync(bcnt, 0, (size_t)NB * 4, stream);
    hipMemsetAsync(bfill, 0, (size_t)NB * 4, stream);
    hipMemsetAsync(g, 0, (size_t)NUM_GRAPHS * HID * 4, stream);

    k_prepW<<<K1, 128, 0, stream>>>(W1, Wt1, K1, K1 + 8);
    k_prepW<<<HID, 128, 0, stream>>>(W2, Wt2, HID, HID + 8);
    k_prepW<<<HID, 128, 0, stream>>>(W3, Wt3, HID, HID + 8);
    k_prepA<<<(N_NODES + 3) / 4, 256, 0, stream>>>(x, nidx, emb, Abu);

    k_bhist<<<512, 256, 0, stream>>>(dstA, bcnt);
    k_bscan<<<1, 512, 0, stream>>>(bcnt, boff, rowptr);
    k_passA<<<(N_EDGES + EPB - 1) / EPB, 256, 0, stream>>>(srcA, dstA, boff, bfill, barr);
    k_passB<<<NB, 256, 0, stream>>>(barr, boff, rowptr, csr);

    int gemmBlocks = (N_NODES + 63) / 64;  // 782
    int aggrBlocks = (N_NODES + 3) / 4;    // 12500

    k_mgemm<K1><<<gemmBlocks, 256, 0, stream>>>((const unsigned short*)Abu, Wt1, a1s, a1d, hLin, asn, adn);
    k_aggr<false><<<aggrBlocks, 256, 0, stream>>>(rowptr, csr, asn, adn, hLin, b1, hAct);
    k_mgemm<HID><<<gemmBlocks, 256, 0, stream>>>(hAct, Wt2, a2s, a2d, hLin, asn, adn);
    k_aggr<false><<<aggrBlocks, 256, 0, stream>>>(rowptr, csr, asn, adn, hLin, b2, hAct);
    k_mgemm<HID><<<gemmBlocks, 256, 0, stream>>>(hAct, Wt3, a3s, a3d, hLin, asn, adn);
    k_aggr<true><<<aggrBlocks, 256, 0, stream>>>(rowptr, csr, asn, adn, hLin, b3, h3f);

    k_pool<<<(N_NODES + 127) / 128, 128, 0, stream>>>(h3f, batch, g);
    k_fc<<<(NUM_GRAPHS * OUT_DIM + 255) / 256, 256, 0, stream>>>(g, fcW, fcb, out);
}

// Round 5
// 334.272 us; speedup vs baseline: 1.6932x; 1.1148x over previous
//
#include <hip/hip_runtime.h>

#define N_NODES 50000
#define N_EDGES 800000
#define IN_DIM 128
#define EMB_DIM 64
#define HID 128
#define OUT_DIM 64
#define NUM_GRAPHS 128
#define E_TOT (N_EDGES + N_NODES)
#define K1 (IN_DIM + EMB_DIM)   // 192
#define NB 391                   // ceil(N_NODES/128) buckets of 128 dst nodes
#define EPT 16
#define EPB (256 * EPT)          // 4096 edges per passA block

typedef __attribute__((ext_vector_type(8))) short bf16x8;
typedef __attribute__((ext_vector_type(4))) float f32x4;

__device__ __forceinline__ float gelu_f(float x) {
    float x3 = x * x * x;
    return 0.5f * x * (1.0f + tanhf(0.7978845608028654f * (x + 0.044715f * x3)));
}
__device__ __forceinline__ float lrelu02(float x) { return x > 0.f ? x : 0.2f * x; }
__device__ __forceinline__ float rl_f(float v, int j) {
    return __int_as_float(__builtin_amdgcn_readlane(__float_as_int(v), j));
}
__device__ __forceinline__ unsigned short f2bf(float f) {  // RNE
    unsigned u = __float_as_uint(f);
    unsigned r = (u + 0x7fffu + ((u >> 16) & 1u)) >> 16;
    return (unsigned short)r;
}
__device__ __forceinline__ unsigned pk2bf(float a, float b) {
    return (unsigned)f2bf(a) | ((unsigned)f2bf(b) << 16);
}

// ---------- zero bcnt + bfill (replaces memsets; g buffer eliminated) ----------
__global__ __launch_bounds__(256) void k_zero(int* __restrict__ bcnt, int* __restrict__ bfill) {
    int t = blockIdx.x * 256 + threadIdx.x;
    if (t < NB) { bcnt[t] = 0; bfill[t] = 0; }
}

// ---------- prep all three W^T bf16 padded in one launch ----------
__global__ __launch_bounds__(128) void k_prepW3(const float* __restrict__ W1, unsigned short* __restrict__ Wt1,
                                                const float* __restrict__ W2, unsigned short* __restrict__ Wt2,
                                                const float* __restrict__ W3, unsigned short* __restrict__ Wt3) {
    int b = blockIdx.x;
    int c = threadIdx.x;
    if (b < K1) {
        Wt1[(size_t)c * (K1 + 8) + b] = f2bf(W1[(size_t)b * HID + c]);
    } else if (b < K1 + HID) {
        int k = b - K1;
        Wt2[(size_t)c * (HID + 8) + k] = f2bf(W2[(size_t)k * HID + c]);
    } else {
        int k = b - K1 - HID;
        Wt3[(size_t)c * (HID + 8) + k] = f2bf(W3[(size_t)k * HID + c]);
    }
}

// ---------- prep A for layer 1: Abf[n] = [x[n]/||x[n]|| | emb[nidx[n]]] bf16 [N,192] ----------
__global__ __launch_bounds__(256) void k_prepA(const float* __restrict__ x, const int* __restrict__ nidx,
                                               const float* __restrict__ emb, unsigned* __restrict__ Abu) {
    int lane = threadIdx.x & 63;
    int node = (blockIdx.x * 256 + threadIdx.x) >> 6;
    if (node >= N_NODES) return;
    float2 v = ((const float2*)(x + (size_t)node * IN_DIM))[lane];
    float ss = v.x * v.x + v.y * v.y;
#pragma unroll
    for (int o = 32; o; o >>= 1) ss += __shfl_xor(ss, o);
    float nrm = sqrtf(ss);
    if (nrm == 0.f) nrm = 1e-8f;
    float inv = 1.f / nrm;
    unsigned* row = Abu + (size_t)node * (K1 / 2);
    row[lane] = pk2bf(v.x * inv, v.y * inv);
    int nid = __builtin_amdgcn_readfirstlane(nidx[node]);
    if (lane < 32) {
        float2 e = ((const float2*)(emb + (size_t)nid * EMB_DIM))[lane];
        row[64 + lane] = pk2bf(e.x, e.y);
    }
}

// ---------- bucket histogram (LDS-aggregated) ----------
__global__ __launch_bounds__(256) void k_bhist(const int* __restrict__ dst, int* __restrict__ bcnt) {
    __shared__ int h[NB];
    for (int i = threadIdx.x; i < NB; i += 256) h[i] = 0;
    __syncthreads();
    for (int e = blockIdx.x * 256 + threadIdx.x; e < N_EDGES; e += gridDim.x * 256)
        atomicAdd(&h[dst[e] >> 7], 1);
    __syncthreads();
    for (int i = threadIdx.x; i < NB; i += 256)
        if (h[i]) atomicAdd(&bcnt[i], h[i]);
}

// ---------- scan bucket counts -> boff[NB+1]; also rowptr[N]=E_TOT ----------
__global__ __launch_bounds__(512) void k_bscan(const int* __restrict__ bcnt, int* __restrict__ boff,
                                               int* __restrict__ rowptr) {
    __shared__ int sh[512];
    int t = threadIdx.x;
    int v = (t < NB) ? bcnt[t] : 0;
    sh[t] = v;
    __syncthreads();
    for (int o = 1; o < 512; o <<= 1) {
        int u = (t >= o) ? sh[t - o] : 0;
        __syncthreads();
        sh[t] += u;
        __syncthreads();
    }
    if (t < NB) boff[t] = sh[t] - v;
    if (t == NB - 1) boff[NB] = sh[t];
    if (t == 0) rowptr[N_NODES] = E_TOT;
}

// ---------- pass A: partition edges into bucket-major array (4B packed: src | dstlow<<16) ----------
__global__ __launch_bounds__(256) void k_passA(const int* __restrict__ src, const int* __restrict__ dst,
                                               const int* __restrict__ boff, int* __restrict__ bfill,
                                               unsigned* __restrict__ barr) {
    __shared__ int h[NB];
    __shared__ int base[NB];
    for (int i = threadIdx.x; i < NB; i += 256) h[i] = 0;
    __syncthreads();
    int e0 = blockIdx.x * EPB;
    int tag[EPT];
#pragma unroll
    for (int i = 0; i < EPT; i++) {
        int e = e0 + i * 256 + threadIdx.x;
        tag[i] = -1;
        if (e < N_EDGES) {
            int b = dst[e] >> 7;
            int r = atomicAdd(&h[b], 1);  // rank within (block,bucket); r < 4096
            tag[i] = (b << 12) | r;
        }
    }
    __syncthreads();
    for (int i = threadIdx.x; i < NB; i += 256)
        base[i] = h[i] ? atomicAdd(&bfill[i], h[i]) : 0;
    __syncthreads();
#pragma unroll
    for (int i = 0; i < EPT; i++) {
        if (tag[i] >= 0) {
            int e = e0 + i * 256 + threadIdx.x;
            int b = tag[i] >> 12, r = tag[i] & 0xfff;
            unsigned s = (unsigned)src[e];
            unsigned dl = (unsigned)(dst[e] & 127);
            barr[boff[b] + base[b] + r] = s | (dl << 16);  // src fits 16 bits (N<65536)
        }
    }
}

// ---------- pass B: per bucket, build rowptr + csr (self loop at slot 0) ----------
__global__ __launch_bounds__(256) void k_passB(const unsigned* __restrict__ barr, const int* __restrict__ boff,
                                               int* __restrict__ rowptr, int* __restrict__ csr) {
    __shared__ int dcnt[128];
    __shared__ int dsum[128];
    __shared__ int locOff[128];
    int b = blockIdx.x;
    int t = threadIdx.x;
    int n0 = b << 7;
    int cnt = min(128, N_NODES - n0);
    int eb = boff[b], ee = boff[b + 1];
    if (t < 128) dcnt[t] = 0;
    __syncthreads();
    for (int i = eb + t; i < ee; i += 256) atomicAdd(&dcnt[barr[i] >> 16], 1);
    __syncthreads();
    int v = 0;
    if (t < 128) {
        v = (t < cnt) ? dcnt[t] + 1 : 0;  // +1 self loop
        dsum[t] = v;
    }
    __syncthreads();
    for (int o = 1; o < 128; o <<= 1) {
        int u = (t >= o && t < 128) ? dsum[t - o] : 0;
        __syncthreads();
        if (t < 128) dsum[t] += u;
        __syncthreads();
    }
    int csrBase = eb + n0;
    if (t < 128) {
        locOff[t] = dsum[t] - v;
        dcnt[t] = 0;
    }
    if (t < cnt) {
        int loc = dsum[t] - v;
        rowptr[n0 + t] = csrBase + loc;
        csr[csrBase + loc] = n0 + t;  // self loop
    }
    __syncthreads();
    for (int i = eb + t; i < ee; i += 256) {
        unsigned vv = barr[i];
        int dl = vv >> 16;
        int s = (int)(vv & 0xffffu);
        int k = atomicAdd(&dcnt[dl], 1);
        csr[csrBase + locOff[dl] + 1 + k] = s;
    }
}

// ---------- MFMA GEMM: Hbf[N,128] = Abf[N,K] @ W, asn/adn from fp32 acc ----------
template <int K>
__global__ __launch_bounds__(256) void k_mgemm(const unsigned short* __restrict__ Abf,
                                               const unsigned short* __restrict__ WtP,
                                               const float* __restrict__ a_s, const float* __restrict__ a_d,
                                               unsigned short* __restrict__ Hbf,
                                               float* __restrict__ asn, float* __restrict__ adn) {
    constexpr int KP = K + 8;
    constexpr int NK = K / 32;
    __shared__ __align__(16) unsigned short Wl[128 * KP];
    {
        const uint4* gsrc = (const uint4*)WtP;
        uint4* ldst = (uint4*)Wl;
        const int nchunk = 128 * KP * 2 / 16;
        for (int i = threadIdx.x; i < nchunk; i += 256) ldst[i] = gsrc[i];
    }
    int lane = threadIdx.x & 63;
    int wv = threadIdx.x >> 6;
    int rowbase = blockIdx.x * 64 + wv * 16;
    if (rowbase >= N_NODES) { __syncthreads(); return; }
    int l15 = lane & 15, quad = lane >> 4;

    // prefetch all A fragments (independent global loads, issued before the wait)
    const unsigned short* Abase = Abf + (size_t)(rowbase + l15) * K + quad * 8;
    bf16x8 afr[NK];
#pragma unroll
    for (int i = 0; i < NK; i++) afr[i] = *(const bf16x8*)(Abase + i * 32);

    __syncthreads();

    f32x4 acc[8];
#pragma unroll
    for (int t = 0; t < 8; t++) acc[t] = (f32x4){0.f, 0.f, 0.f, 0.f};
#pragma unroll
    for (int i = 0; i < NK; i++) {
#pragma unroll
        for (int t = 0; t < 8; t++) {
            bf16x8 bf = *(const bf16x8*)(&Wl[(t * 16 + l15) * KP + i * 32 + quad * 8]);
            acc[t] = __builtin_amdgcn_mfma_f32_16x16x32_bf16(afr[i], bf, acc[t], 0, 0, 0);
        }
    }
    float asc[8], adc[8];
#pragma unroll
    for (int t = 0; t < 8; t++) { asc[t] = a_s[t * 16 + l15]; adc[t] = a_d[t * 16 + l15]; }
#pragma unroll
    for (int r = 0; r < 4; r++) {
        int row = rowbase + quad * 4 + r;
        float ps = 0.f, pd = 0.f;
#pragma unroll
        for (int t = 0; t < 8; t++) {
            float v = acc[t][r];
            Hbf[(size_t)row * HID + t * 16 + l15] = f2bf(v);
            ps = fmaf(v, asc[t], ps);
            pd = fmaf(v, adc[t], pd);
        }
#pragma unroll
        for (int o = 1; o < 16; o <<= 1) {
            ps += __shfl_xor(ps, o);
            pd += __shfl_xor(pd, o);
        }
        if (l15 == 0) { asn[row] = ps; adn[row] = pd; }
    }
}

// ---------- GAT aggregation: wave per dst node, bf16 gather ----------
template <bool OUT32>
__global__ __launch_bounds__(256) void k_aggr(const int* __restrict__ rowptr, const int* __restrict__ csr,
                                              const float* __restrict__ asn, const float* __restrict__ adn,
                                              const unsigned short* __restrict__ hbf,
                                              const float* __restrict__ bias, void* __restrict__ outp) {
    __shared__ float sh_e[4][64];
    __shared__ int sh_s[4][64];
    int lane = threadIdx.x & 63;
    int w = threadIdx.x >> 6;
    int node = blockIdx.x * 4 + w;
    if (node >= N_NODES) return;
    int st = rowptr[node], en = rowptr[node + 1];
    int deg = en - st;
    float ad = adn[node];
    const unsigned* hu = (const unsigned*)hbf;
    float2 acc = make_float2(0.f, 0.f);

    if (deg <= 64) {
        int s = 0;
        float l = -1e30f;
        if (lane < deg) {
            s = csr[st + lane];
            l = lrelu02(asn[s] + ad);
        }
        float m = l;
#pragma unroll
        for (int o = 32; o; o >>= 1) m = fmaxf(m, __shfl_xor(m, o));
        float e = (lane < deg) ? __expf(l - m) : 0.f;
        float ssum = e;
#pragma unroll
        for (int o = 32; o; o >>= 1) ssum += __shfl_xor(ssum, o);
        float coef = e / ssum;
        int j = 0;
        for (; j + 8 <= deg; j += 8) {
            int si[8];
            float ci[8];
            unsigned vi[8];
#pragma unroll
            for (int q = 0; q < 8; q++) {
                si[q] = __builtin_amdgcn_readlane(s, j + q);
                ci[q] = rl_f(coef, j + q);
            }
#pragma unroll
            for (int q = 0; q < 8; q++) vi[q] = hu[(size_t)si[q] * 64 + lane];
#pragma unroll
            for (int q = 0; q < 8; q++) {
                acc.x = fmaf(ci[q], __int_as_float(vi[q] << 16), acc.x);
                acc.y = fmaf(ci[q], __int_as_float(vi[q] & 0xffff0000u), acc.y);
            }
        }
        for (; j + 4 <= deg; j += 4) {
            int s0 = __builtin_amdgcn_readlane(s, j);
            int s1 = __builtin_amdgcn_readlane(s, j + 1);
            int s2 = __builtin_amdgcn_readlane(s, j + 2);
            int s3 = __builtin_amdgcn_readlane(s, j + 3);
            float c0 = rl_f(coef, j), c1 = rl_f(coef, j + 1);
            float c2 = rl_f(coef, j + 2), c3 = rl_f(coef, j + 3);
            unsigned v0 = hu[(size_t)s0 * 64 + lane];
            unsigned v1 = hu[(size_t)s1 * 64 + lane];
            unsigned v2 = hu[(size_t)s2 * 64 + lane];
            unsigned v3 = hu[(size_t)s3 * 64 + lane];
            acc.x = fmaf(c0, __int_as_float(v0 << 16), acc.x);
            acc.y = fmaf(c0, __int_as_float(v0 & 0xffff0000u), acc.y);
            acc.x = fmaf(c1, __int_as_float(v1 << 16), acc.x);
            acc.y = fmaf(c1, __int_as_float(v1 & 0xffff0000u), acc.y);
            acc.x = fmaf(c2, __int_as_float(v2 << 16), acc.x);
            acc.y = fmaf(c2, __int_as_float(v2 & 0xffff0000u), acc.y);
            acc.x = fmaf(c3, __int_as_float(v3 << 16), acc.x);
            acc.y = fmaf(c3, __int_as_float(v3 & 0xffff0000u), acc.y);
        }
        for (; j < deg; j++) {
            int s0 = __builtin_amdgcn_readlane(s, j);
            float c0 = rl_f(coef, j);
            unsigned v0 = hu[(size_t)s0 * 64 + lane];
            acc.x = fmaf(c0, __int_as_float(v0 << 16), acc.x);
            acc.y = fmaf(c0, __int_as_float(v0 & 0xffff0000u), acc.y);
        }
    } else {
        float m = -1e30f;
        for (int i = st + lane; i < en; i += 64) {
            float l = lrelu02(asn[csr[i]] + ad);
            m = fmaxf(m, l);
        }
#pragma unroll
        for (int o = 32; o; o >>= 1) m = fmaxf(m, __shfl_xor(m, o));
        float ssum = 0.f;
        for (int i = st + lane; i < en; i += 64) {
            float l = lrelu02(asn[csr[i]] + ad);
            ssum += __expf(l - m);
        }
#pragma unroll
        for (int o = 32; o; o >>= 1) ssum += __shfl_xor(ssum, o);
        float inv = 1.f / ssum;
        for (int base = st; base < en; base += 64) {
            int cnt = min(64, en - base);
            if (lane < cnt) {
                int sx = csr[base + lane];
                float l = lrelu02(asn[sx] + ad);
                sh_e[w][lane] = __expf(l - m) * inv;
                sh_s[w][lane] = sx;
            }
            for (int j = 0; j < cnt; j++) {
                float c = sh_e[w][j];
                int sx = sh_s[w][j];
                unsigned v0 = hu[(size_t)sx * 64 + lane];
                acc.x = fmaf(c, __int_as_float(v0 << 16), acc.x);
                acc.y = fmaf(c, __int_as_float(v0 & 0xffff0000u), acc.y);
            }
        }
    }
    float2 b = ((const float2*)bias)[lane];
    float rx = gelu_f(acc.x + b.x);
    float ry = gelu_f(acc.y + b.y);
    if constexpr (OUT32) {
        ((float2*)outp)[(size_t)node * 64 + lane] = make_float2(rx, ry);
    } else {
        ((unsigned*)outp)[(size_t)node * 64 + lane] = pk2bf(rx, ry);
    }
}

// ---------- fused global_add_pool + fc + leaky_relu: one block per graph ----------
__global__ __launch_bounds__(256) void k_poolfc(const float* __restrict__ h, const int* __restrict__ batch,
                                                const float* __restrict__ fcW, const float* __restrict__ fcb,
                                                float* __restrict__ out) {
    __shared__ float gv[HID];
    __shared__ float tmp[256];
    int g = blockIdx.x;
    // lower_bound(batch, g) and lower_bound(batch, g+1) on sorted batch
    int st, en;
    {
        int lo = 0, hi = N_NODES;
        while (lo < hi) { int mid = (lo + hi) >> 1; if (batch[mid] < g) lo = mid + 1; else hi = mid; }
        st = lo;
        lo = st; hi = N_NODES;
        while (lo < hi) { int mid = (lo + hi) >> 1; if (batch[mid] < g + 1) lo = mid + 1; else hi = mid; }
        en = lo;
    }
    int c = threadIdx.x & 127;
    int half = threadIdx.x >> 7;  // 2-way row parallel
    float acc = 0.f;
#pragma unroll 4
    for (int n = st + half; n < en; n += 2) acc += h[(size_t)n * HID + c];
    tmp[threadIdx.x] = acc;
    __syncthreads();
    if (threadIdx.x < HID) gv[threadIdx.x] = tmp[threadIdx.x] + tmp[threadIdx.x + 128];
    __syncthreads();
    if (threadIdx.x < OUT_DIM) {
        float a = fcb[threadIdx.x];
#pragma unroll 4
        for (int k = 0; k < HID; k++) a = fmaf(gv[k], fcW[k * OUT_DIM + threadIdx.x], a);
        out[g * OUT_DIM + threadIdx.x] = a > 0.f ? a : 0.01f * a;
    }
}

extern "C" void kernel_launch(void* const* d_in, const int* in_sizes, int n_in,
                              void* d_out, int out_size, void* d_ws, size_t ws_size,
                              hipStream_t stream) {
    const float* x    = (const float*)d_in[0];
    const int* nidx   = (const int*)d_in[1];
    const int* ei     = (const int*)d_in[2];
    const int* batch  = (const int*)d_in[3];
    const float* emb  = (const float*)d_in[4];
    const float* W1   = (const float*)d_in[5];
    const float* a1s  = (const float*)d_in[6];
    const float* a1d  = (const float*)d_in[7];
    const float* b1   = (const float*)d_in[8];
    const float* W2   = (const float*)d_in[9];
    const float* a2s  = (const float*)d_in[10];
    const float* a2d  = (const float*)d_in[11];
    const float* b2   = (const float*)d_in[12];
    const float* W3   = (const float*)d_in[13];
    const float* a3s  = (const float*)d_in[14];
    const float* a3d  = (const float*)d_in[15];
    const float* b3   = (const float*)d_in[16];
    const float* fcW  = (const float*)d_in[17];
    const float* fcb  = (const float*)d_in[18];
    float* out = (float*)d_out;
    const int* srcA = ei;
    const int* dstA = ei + N_EDGES;

    char* w = (char*)d_ws;
    auto alloc = [&](size_t bytes) -> char* {
        char* p = w;
        w += (bytes + 511) & ~(size_t)511;
        return p;
    };
    // region0: Abf [N,192] bf16 during prep+GEMM1; later h3f fp32 [N,128]
    char* region0 = alloc((size_t)N_NODES * HID * 4);
    unsigned* Abu = (unsigned*)region0;
    float* h3f    = (float*)region0;
    unsigned short* hLin = (unsigned short*)alloc((size_t)N_NODES * HID * 2);
    unsigned short* hAct = (unsigned short*)alloc((size_t)N_NODES * HID * 2);
    float* asn   = (float*)alloc((size_t)N_NODES * 4);
    float* adn   = (float*)alloc((size_t)N_NODES * 4);
    int* rowptr  = (int*)alloc((size_t)(N_NODES + 1) * 4);
    int* bcnt    = (int*)alloc((size_t)NB * 4);
    int* boff    = (int*)alloc((size_t)(NB + 1) * 4);
    int* bfill   = (int*)alloc((size_t)NB * 4);
    unsigned* barr = (unsigned*)alloc((size_t)N_EDGES * 4);
    int* csr     = (int*)alloc((size_t)E_TOT * 4);
    unsigned short* Wt1 = (unsigned short*)alloc((size_t)HID * (K1 + 8) * 2);
    unsigned short* Wt2 = (unsigned short*)alloc((size_t)HID * (HID + 8) * 2);
    unsigned short* Wt3 = (unsigned short*)alloc((size_t)HID * (HID + 8) * 2);

    k_zero<<<(NB + 255) / 256, 256, 0, stream>>>(bcnt, bfill);
    k_prepW3<<<K1 + 2 * HID, 128, 0, stream>>>(W1, Wt1, W2, Wt2, W3, Wt3);
    k_prepA<<<(N_NODES + 3) / 4, 256, 0, stream>>>(x, nidx, emb, Abu);

    k_bhist<<<512, 256, 0, stream>>>(dstA, bcnt);
    k_bscan<<<1, 512, 0, stream>>>(bcnt, boff, rowptr);
    k_passA<<<(N_EDGES + EPB - 1) / EPB, 256, 0, stream>>>(srcA, dstA, boff, bfill, barr);
    k_passB<<<NB, 256, 0, stream>>>(barr, boff, rowptr, csr);

    int gemmBlocks = (N_NODES + 63) / 64;  // 782
    int aggrBlocks = (N_NODES + 3) / 4;    // 12500

    k_mgemm<K1><<<gemmBlocks, 256, 0, stream>>>((const unsigned short*)Abu, Wt1, a1s, a1d, hLin, asn, adn);
    k_aggr<false><<<aggrBlocks, 256, 0, stream>>>(rowptr, csr, asn, adn, hLin, b1, hAct);
    k_mgemm<HID><<<gemmBlocks, 256, 0, stream>>>(hAct, Wt2, a2s, a2d, hLin, asn, adn);
    k_aggr<false><<<aggrBlocks, 256, 0, stream>>>(rowptr, csr, asn, adn, hLin, b2, hAct);
    k_mgemm<HID><<<gemmBlocks, 256, 0, stream>>>(hAct, Wt3, a3s, a3d, hLin, asn, adn);
    k_aggr<true><<<aggrBlocks, 256, 0, stream>>>(rowptr, csr, asn, adn, hLin, b3, h3f);

    k_poolfc<<<NUM_GRAPHS, 256, 0, stream>>>(h3f, batch, fcW, fcb, out);
}